// Round 1
// baseline (528.136 us; speedup 1.0000x reference)
//
#include <hip/hip_runtime.h>
#include <math.h>

// ---------------------------------------------------------------------------
// VariationalGCNEncoder: N=50000 nodes, E=800000 edges, 128 -> 64 -> {32,32}
//   deg[n]  = 1 + #incoming edges ; dinv = 1/sqrt(deg)
//   h       = relu( scatter_dst( dinv[s]*dinv[d] * (x@W1)[s] ) + dinv^2*(x@W1) + b1 )
//   t2      = relu(h) @ [W_mu | W_ls]          (fused two output heads)
//   out_mu  = scatter + self + b_mu ; out_ls likewise
// Workspace layout (floats): deg/dinv [N] | h_pre [N*64] (aliased as t2) | h_acc [N*64]
// ---------------------------------------------------------------------------

__device__ __forceinline__ void atomAddF(float* p, float v) {
    unsafeAtomicAdd(p, v);   // guaranteed global_atomic_add_f32 on gfx950
}

__global__ void k_deg_init(float* __restrict__ deg, int N) {
    int i = blockIdx.x * blockDim.x + threadIdx.x;
    if (i < N) deg[i] = 1.0f;   // self loop
}

__global__ void k_deg_count(const int* __restrict__ dst, float* __restrict__ deg, int E) {
    int i = blockIdx.x * blockDim.x + threadIdx.x;
    if (i < E) atomAddF(&deg[dst[i]], 1.0f);
}

__global__ void k_dinv(float* __restrict__ deg, int N) {
    int i = blockIdx.x * blockDim.x + threadIdx.x;
    if (i < N) deg[i] = 1.0f / sqrtf(deg[i]);   // deg >= 1 always (self loops)
}

// h_pre[N,64] = x[N,128] @ W1[128,64]
__global__ __launch_bounds__(256) void k_gemm1(const float* __restrict__ x,
                                               const float* __restrict__ W,
                                               float* __restrict__ h, int N) {
    __shared__ float xs[32][128];   // 16 KB
    __shared__ float ws[128][64];   // 32 KB
    const int tid = threadIdx.x;
    {   // stage W1 (8192 floats = 2048 float4)
        const float4* W4 = (const float4*)W;
        float4* s4 = (float4*)&ws[0][0];
        #pragma unroll
        for (int i = 0; i < 8; ++i) s4[tid + 256 * i] = W4[tid + 256 * i];
    }
    const int row0 = blockIdx.x * 32;
    {   // stage x tile (32 rows x 128 = 1024 float4)
        const float4* x4 = (const float4*)x;
        float4* s4 = (float4*)&xs[0][0];
        #pragma unroll
        for (int i = 0; i < 4; ++i) {
            int idx = tid + 256 * i;           // 0..1023, 32 float4/row
            int r = idx >> 5, c = idx & 31;
            float4 v = make_float4(0.f, 0.f, 0.f, 0.f);
            if (row0 + r < N) v = x4[(size_t)(row0 + r) * 32 + c];
            s4[idx] = v;
        }
    }
    __syncthreads();
    const int col = tid & 63;     // output feature
    const int rg  = tid >> 6;     // wave id -> rows rg*8 .. rg*8+7
    float acc[8] = {0, 0, 0, 0, 0, 0, 0, 0};
    for (int k = 0; k < 128; ++k) {
        float w = ws[k][col];                       // 2-way bank alias: free
        #pragma unroll
        for (int j = 0; j < 8; ++j) acc[j] += xs[rg * 8 + j][k] * w;  // wave-broadcast
    }
    #pragma unroll
    for (int j = 0; j < 8; ++j) {
        int r = row0 + rg * 8 + j;
        if (r < N) h[(size_t)r * 64 + col] = acc[j];
    }
}

// h_acc = dinv^2 * h_pre + b1   (self-loop term + bias as accumulator init)
__global__ void k_init_h(const float* __restrict__ h_pre, const float* __restrict__ dinv,
                         const float* __restrict__ b1, float* __restrict__ h_acc, int N) {
    int i = blockIdx.x * blockDim.x + threadIdx.x;
    if (i >= N * 64) return;
    int n = i >> 6, f = i & 63;
    float dv = dinv[n];
    h_acc[i] = dv * dv * h_pre[i] + b1[f];
}

// h_acc[dst] += dinv[s]*dinv[d] * h_pre[src]  — one thread per (edge, feature)
__global__ void k_scatter1(const float* __restrict__ h_pre, const float* __restrict__ dinv,
                           const int* __restrict__ src, const int* __restrict__ dst,
                           float* __restrict__ h_acc, int E) {
    int i = blockIdx.x * blockDim.x + threadIdx.x;   // E*64 = 51.2M < 2^31
    if (i >= E * 64) return;
    int e = i >> 6, f = i & 63;
    int s = src[e], d = dst[e];
    float nrm = dinv[s] * dinv[d];
    atomAddF(&h_acc[(size_t)d * 64 + f], nrm * h_pre[(size_t)s * 64 + f]);
}

// t2[N,64] = relu(h_acc)[N,64] @ [W_mu | W_ls][64,64]
__global__ __launch_bounds__(256) void k_gemm2(const float* __restrict__ h_acc,
                                               const float* __restrict__ Wmu,
                                               const float* __restrict__ Wls,
                                               float* __restrict__ t2, int N) {
    __shared__ float hs[32][64];   // 8 KB
    __shared__ float ws[64][64];   // 16 KB
    const int tid = threadIdx.x;
    #pragma unroll
    for (int i = 0; i < 8; ++i) {  // 2048 elements per head
        int idx = tid + 256 * i;
        int k = idx >> 5, j = idx & 31;
        ws[k][j]      = Wmu[idx];
        ws[k][j + 32] = Wls[idx];
    }
    const int row0 = blockIdx.x * 32;
    {
        const float4* h4 = (const float4*)h_acc;
        float4* s4 = (float4*)&hs[0][0];
        #pragma unroll
        for (int i = 0; i < 2; ++i) {
            int idx = tid + 256 * i;            // 0..511, 16 float4/row
            int r = idx >> 4, c = idx & 15;
            float4 v = make_float4(0.f, 0.f, 0.f, 0.f);
            if (row0 + r < N) v = h4[(size_t)(row0 + r) * 16 + c];
            v.x = fmaxf(v.x, 0.f); v.y = fmaxf(v.y, 0.f);
            v.z = fmaxf(v.z, 0.f); v.w = fmaxf(v.w, 0.f);
            s4[idx] = v;                        // relu fused here
        }
    }
    __syncthreads();
    const int col = tid & 63;
    const int rg  = tid >> 6;
    float acc[8] = {0, 0, 0, 0, 0, 0, 0, 0};
    for (int k = 0; k < 64; ++k) {
        float w = ws[k][col];
        #pragma unroll
        for (int j = 0; j < 8; ++j) acc[j] += hs[rg * 8 + j][k] * w;
    }
    #pragma unroll
    for (int j = 0; j < 8; ++j) {
        int r = row0 + rg * 8 + j;
        if (r < N) t2[(size_t)r * 64 + col] = acc[j];
    }
}

// d_out init: mu[n,f] = dinv^2*t2[n,f] + b_mu[f] ; ls[n,f] = dinv^2*t2[n,32+f] + b_ls[f]
__global__ void k_init_out(const float* __restrict__ t2, const float* __restrict__ dinv,
                           const float* __restrict__ bmu, const float* __restrict__ bls,
                           float* __restrict__ out, int N) {
    int i = blockIdx.x * blockDim.x + threadIdx.x;
    if (i >= N * 64) return;
    int n = i >> 6, f = i & 63;
    float dv = dinv[n];
    float v = dv * dv * t2[i];
    if (f < 32) out[(size_t)n * 32 + f] = v + bmu[f];
    else        out[(size_t)N * 32 + (size_t)n * 32 + (f - 32)] = v + bls[f - 32];
}

__global__ void k_scatter2(const float* __restrict__ t2, const float* __restrict__ dinv,
                           const int* __restrict__ src, const int* __restrict__ dst,
                           float* __restrict__ out, int N, int E) {
    int i = blockIdx.x * blockDim.x + threadIdx.x;
    if (i >= E * 64) return;
    int e = i >> 6, f = i & 63;
    int s = src[e], d = dst[e];
    float nrm = dinv[s] * dinv[d];
    float v = nrm * t2[(size_t)s * 64 + f];
    float* p = (f < 32) ? &out[(size_t)d * 32 + f]
                        : &out[(size_t)N * 32 + (size_t)d * 32 + (f - 32)];
    atomAddF(p, v);
}

extern "C" void kernel_launch(void* const* d_in, const int* in_sizes, int n_in,
                              void* d_out, int out_size, void* d_ws, size_t ws_size,
                              hipStream_t stream) {
    const float* x   = (const float*)d_in[0];
    const int*   ei  = (const int*)d_in[1];
    const float* W1  = (const float*)d_in[2];
    const float* b1  = (const float*)d_in[3];
    const float* Wmu = (const float*)d_in[4];
    const float* bmu = (const float*)d_in[5];
    const float* Wls = (const float*)d_in[6];
    const float* bls = (const float*)d_in[7];
    float* out = (float*)d_out;

    const int N = in_sizes[0] / 128;          // 50000
    const int E = in_sizes[1] / 2;            // 800000
    const int* src = ei;                       // edge_index[0]
    const int* dst = ei + E;                   // edge_index[1]

    float* ws    = (float*)d_ws;
    float* deg   = ws;                               // N floats (becomes dinv)
    float* h_pre = ws + ((N + 255) & ~255);          // N*64 (aliased as t2 later)
    float* h_acc = h_pre + (size_t)N * 64;           // N*64
    float* t2    = h_pre;                            // h_pre dead after scatter1

    const int nf = N * 64;
    const int ef = E * 64;

    k_deg_init <<<(N  + 255) / 256, 256, 0, stream>>>(deg, N);
    k_deg_count<<<(E  + 255) / 256, 256, 0, stream>>>(dst, deg, E);
    k_dinv     <<<(N  + 255) / 256, 256, 0, stream>>>(deg, N);
    k_gemm1    <<<(N  +  31) /  32, 256, 0, stream>>>(x, W1, h_pre, N);
    k_init_h   <<<(nf + 255) / 256, 256, 0, stream>>>(h_pre, deg, b1, h_acc, N);
    k_scatter1 <<<(ef + 255) / 256, 256, 0, stream>>>(h_pre, deg, src, dst, h_acc, E);
    k_gemm2    <<<(N  +  31) /  32, 256, 0, stream>>>(h_acc, Wmu, Wls, t2, N);
    k_init_out <<<(nf + 255) / 256, 256, 0, stream>>>(t2, deg, bmu, bls, out, N);
    k_scatter2 <<<(ef + 255) / 256, 256, 0, stream>>>(t2, deg, src, dst, out, N, E);
}

// Round 2
// 310.439 us; speedup vs baseline: 1.7013x; 1.7013x over previous
//
#include <hip/hip_runtime.h>
#include <math.h>

// ---------------------------------------------------------------------------
// VariationalGCNEncoder: N=50000, E=800000, 128 -> 64 -> {32,32}
// R2: CSR-by-dst + gather-reduce (no per-feature atomics).
//   counts[d] = #in-edges;  deg = counts+1 (self loop);  dinv = rsqrt(deg)
//   CSR: row_ptr (excl. prefix of counts), edge_src[], edge_norm[]=dinv[s]*dinv[d]
//   h_pre = x @ W1                                  (gemm1)
//   h     = relu( sum_e norm*h_pre[src] + dinv^2*h_pre[n] + b1 )   (gather1, fused)
//   t2    = h @ [W_mu | W_ls]                       (gemm2; h already relu'd)
//   out   = sum_e norm*t2[src] + dinv^2*t2[n] + bias (gather2, fused, split mu/ls)
// ---------------------------------------------------------------------------

__global__ void k_zero(int* __restrict__ p, int n) {
    int i = blockIdx.x * blockDim.x + threadIdx.x;
    if (i < n) p[i] = 0;
}

__global__ void k_count(const int* __restrict__ dst, int* __restrict__ counts, int E) {
    int i = blockIdx.x * blockDim.x + threadIdx.x;
    if (i < E) atomicAdd(&counts[dst[i]], 1);
}

// pass 1: per-block exclusive scan of counts -> row_ptr, block sums -> bsum
__global__ __launch_bounds__(256) void k_scan1(const int* __restrict__ counts,
                                               int* __restrict__ row_ptr,
                                               int* __restrict__ bsum, int N) {
    __shared__ int s[256];
    int t = threadIdx.x, i = blockIdx.x * 256 + t;
    int v = (i < N) ? counts[i] : 0;
    s[t] = v;
    __syncthreads();
    #pragma unroll
    for (int off = 1; off < 256; off <<= 1) {
        int x = (t >= off) ? s[t - off] : 0;
        __syncthreads();
        s[t] += x;
        __syncthreads();
    }
    if (i < N) row_ptr[i] = s[t] - v;           // exclusive
    if (t == 255) bsum[blockIdx.x] = s[255];    // block total
}

// pass 2: single block scans block sums (exclusive, in place). nb <= 256
__global__ __launch_bounds__(256) void k_scan2(int* __restrict__ bsum, int nb) {
    __shared__ int s[256];
    int t = threadIdx.x;
    int v = (t < nb) ? bsum[t] : 0;
    s[t] = v;
    __syncthreads();
    #pragma unroll
    for (int off = 1; off < 256; off <<= 1) {
        int x = (t >= off) ? s[t - off] : 0;
        __syncthreads();
        s[t] += x;
        __syncthreads();
    }
    if (t < nb) bsum[t] = s[t] - v;             // exclusive
}

// pass 3: add block offsets; init cursor + dinv; set row_ptr[N]=E
__global__ void k_scan3(int* __restrict__ row_ptr, const int* __restrict__ bsum,
                        const int* __restrict__ counts, int* __restrict__ cursor,
                        float* __restrict__ dinv, int N, int E) {
    int i = blockIdx.x * blockDim.x + threadIdx.x;
    if (i < N) {
        int r = row_ptr[i] + bsum[i >> 8];
        row_ptr[i] = r;
        cursor[i] = r;
        dinv[i] = rsqrtf((float)(counts[i] + 1));
    }
    if (i == 0) row_ptr[N] = E;
}

__global__ void k_fill(const int* __restrict__ src, const int* __restrict__ dst,
                       const float* __restrict__ dinv, int* __restrict__ cursor,
                       int* __restrict__ edge_src, float* __restrict__ edge_norm, int E) {
    int e = blockIdx.x * blockDim.x + threadIdx.x;
    if (e >= E) return;
    int s = src[e], d = dst[e];
    int pos = atomicAdd(&cursor[d], 1);
    edge_src[pos]  = s;
    edge_norm[pos] = dinv[s] * dinv[d];
}

// h_pre[N,64] = x[N,128] @ W1[128,64]
__global__ __launch_bounds__(256) void k_gemm1(const float* __restrict__ x,
                                               const float* __restrict__ W,
                                               float* __restrict__ h, int N) {
    __shared__ float xs[32][128];   // 16 KB
    __shared__ float ws[128][64];   // 32 KB
    const int tid = threadIdx.x;
    {   // stage W1 (8192 floats = 2048 float4)
        const float4* W4 = (const float4*)W;
        float4* s4 = (float4*)&ws[0][0];
        #pragma unroll
        for (int i = 0; i < 8; ++i) s4[tid + 256 * i] = W4[tid + 256 * i];
    }
    const int row0 = blockIdx.x * 32;
    {   // stage x tile (32 rows x 128 = 1024 float4)
        const float4* x4 = (const float4*)x;
        float4* s4 = (float4*)&xs[0][0];
        #pragma unroll
        for (int i = 0; i < 4; ++i) {
            int idx = tid + 256 * i;
            int r = idx >> 5, c = idx & 31;
            float4 v = make_float4(0.f, 0.f, 0.f, 0.f);
            if (row0 + r < N) v = x4[(size_t)(row0 + r) * 32 + c];
            s4[idx] = v;
        }
    }
    __syncthreads();
    const int col = tid & 63;
    const int rg  = tid >> 6;
    float acc[8] = {0, 0, 0, 0, 0, 0, 0, 0};
    for (int k = 0; k < 128; ++k) {
        float w = ws[k][col];
        #pragma unroll
        for (int j = 0; j < 8; ++j) acc[j] += xs[rg * 8 + j][k] * w;
    }
    #pragma unroll
    for (int j = 0; j < 8; ++j) {
        int r = row0 + rg * 8 + j;
        if (r < N) h[(size_t)r * 64 + col] = acc[j];
    }
}

// h[n,f] = relu( dinv[n]^2*h_pre[n,f] + b1[f] + sum_in norm*h_pre[src,f] )
__global__ __launch_bounds__(256) void k_gather1(const float* __restrict__ h_pre,
                                                 const int* __restrict__ row_ptr,
                                                 const int* __restrict__ edge_src,
                                                 const float* __restrict__ edge_norm,
                                                 const float* __restrict__ dinv,
                                                 const float* __restrict__ b1,
                                                 float* __restrict__ h, int N) {
    const int lane = threadIdx.x & 63;
    const int n = blockIdx.x * 4 + (threadIdx.x >> 6);
    if (n >= N) return;
    const int beg = row_ptr[n], end = row_ptr[n + 1];
    const float dv = dinv[n];
    float acc = dv * dv * h_pre[(size_t)n * 64 + lane] + b1[lane];
    int i = beg;
    for (; i + 1 < end; i += 2) {
        int   s0 = edge_src[i],     s1 = edge_src[i + 1];
        float w0 = edge_norm[i],    w1 = edge_norm[i + 1];
        float v0 = h_pre[(size_t)s0 * 64 + lane];
        float v1 = h_pre[(size_t)s1 * 64 + lane];
        acc += w0 * v0;
        acc += w1 * v1;
    }
    if (i < end)
        acc += edge_norm[i] * h_pre[(size_t)edge_src[i] * 64 + lane];
    h[(size_t)n * 64 + lane] = fmaxf(acc, 0.f);
}

// t2[N,64] = h[N,64] @ [W_mu | W_ls][64,64]   (h already relu'd)
__global__ __launch_bounds__(256) void k_gemm2(const float* __restrict__ h,
                                               const float* __restrict__ Wmu,
                                               const float* __restrict__ Wls,
                                               float* __restrict__ t2, int N) {
    __shared__ float hs[32][64];   // 8 KB
    __shared__ float ws[64][64];   // 16 KB
    const int tid = threadIdx.x;
    #pragma unroll
    for (int i = 0; i < 8; ++i) {
        int idx = tid + 256 * i;
        int k = idx >> 5, j = idx & 31;
        ws[k][j]      = Wmu[idx];
        ws[k][j + 32] = Wls[idx];
    }
    const int row0 = blockIdx.x * 32;
    {
        const float4* h4 = (const float4*)h;
        float4* s4 = (float4*)&hs[0][0];
        #pragma unroll
        for (int i = 0; i < 2; ++i) {
            int idx = tid + 256 * i;
            int r = idx >> 4, c = idx & 15;
            float4 v = make_float4(0.f, 0.f, 0.f, 0.f);
            if (row0 + r < N) v = h4[(size_t)(row0 + r) * 16 + c];
            s4[idx] = v;
        }
    }
    __syncthreads();
    const int col = tid & 63;
    const int rg  = tid >> 6;
    float acc[8] = {0, 0, 0, 0, 0, 0, 0, 0};
    for (int k = 0; k < 64; ++k) {
        float w = ws[k][col];
        #pragma unroll
        for (int j = 0; j < 8; ++j) acc[j] += hs[rg * 8 + j][k] * w;
    }
    #pragma unroll
    for (int j = 0; j < 8; ++j) {
        int r = row0 + rg * 8 + j;
        if (r < N) t2[(size_t)r * 64 + col] = acc[j];
    }
}

// out: mu[n,f]=sum+self+b_mu (lane<32, t2 col=lane), ls likewise (lane>=32)
__global__ __launch_bounds__(256) void k_gather2(const float* __restrict__ t2,
                                                 const int* __restrict__ row_ptr,
                                                 const int* __restrict__ edge_src,
                                                 const float* __restrict__ edge_norm,
                                                 const float* __restrict__ dinv,
                                                 const float* __restrict__ bmu,
                                                 const float* __restrict__ bls,
                                                 float* __restrict__ out, int N) {
    const int lane = threadIdx.x & 63;
    const int n = blockIdx.x * 4 + (threadIdx.x >> 6);
    if (n >= N) return;
    const int beg = row_ptr[n], end = row_ptr[n + 1];
    const float dv = dinv[n];
    float bias = (lane < 32) ? bmu[lane] : bls[lane - 32];
    float acc = dv * dv * t2[(size_t)n * 64 + lane] + bias;
    int i = beg;
    for (; i + 1 < end; i += 2) {
        int   s0 = edge_src[i],     s1 = edge_src[i + 1];
        float w0 = edge_norm[i],    w1 = edge_norm[i + 1];
        float v0 = t2[(size_t)s0 * 64 + lane];
        float v1 = t2[(size_t)s1 * 64 + lane];
        acc += w0 * v0;
        acc += w1 * v1;
    }
    if (i < end)
        acc += edge_norm[i] * t2[(size_t)edge_src[i] * 64 + lane];
    if (lane < 32) out[(size_t)n * 32 + lane] = acc;
    else           out[(size_t)N * 32 + (size_t)n * 32 + (lane - 32)] = acc;
}

extern "C" void kernel_launch(void* const* d_in, const int* in_sizes, int n_in,
                              void* d_out, int out_size, void* d_ws, size_t ws_size,
                              hipStream_t stream) {
    const float* x   = (const float*)d_in[0];
    const int*   ei  = (const int*)d_in[1];
    const float* W1  = (const float*)d_in[2];
    const float* b1  = (const float*)d_in[3];
    const float* Wmu = (const float*)d_in[4];
    const float* bmu = (const float*)d_in[5];
    const float* Wls = (const float*)d_in[6];
    const float* bls = (const float*)d_in[7];
    float* out = (float*)d_out;

    const int N = in_sizes[0] / 128;          // 50000
    const int E = in_sizes[1] / 2;            // 800000
    const int* src = ei;
    const int* dst = ei + E;
    const int NB = (N + 255) / 256;           // 196 scan blocks

    // workspace carve-up (each region 1 KiB-aligned)
    char* w = (char*)d_ws;
    auto carve = [&](size_t bytes) { char* p = w; w += (bytes + 1023) & ~(size_t)1023; return p; };
    int*   counts   = (int*)  carve((size_t)N * 4);
    int*   row_ptr  = (int*)  carve((size_t)(N + 1) * 4);
    int*   cursor   = (int*)  carve((size_t)N * 4);
    int*   bsum     = (int*)  carve(256 * 4);
    float* dinv     = (float*)carve((size_t)N * 4);
    int*   edge_src = (int*)  carve((size_t)E * 4);
    float* edge_nrm = (float*)carve((size_t)E * 4);
    float* bufA     = (float*)carve((size_t)N * 64 * 4);   // h_pre, then t2
    float* bufB     = (float*)carve((size_t)N * 64 * 4);   // h

    k_zero   <<<NB, 256, 0, stream>>>(counts, N);
    k_count  <<<(E + 255) / 256, 256, 0, stream>>>(dst, counts, E);
    k_scan1  <<<NB, 256, 0, stream>>>(counts, row_ptr, bsum, N);
    k_scan2  <<<1, 256, 0, stream>>>(bsum, NB);
    k_scan3  <<<NB, 256, 0, stream>>>(row_ptr, bsum, counts, cursor, dinv, N, E);
    k_fill   <<<(E + 255) / 256, 256, 0, stream>>>(src, dst, dinv, cursor, edge_src, edge_nrm, E);
    k_gemm1  <<<(N + 31) / 32, 256, 0, stream>>>(x, W1, bufA, N);
    k_gather1<<<(N + 3) / 4, 256, 0, stream>>>(bufA, row_ptr, edge_src, edge_nrm, dinv, b1, bufB, N);
    k_gemm2  <<<(N + 31) / 32, 256, 0, stream>>>(bufB, Wmu, Wls, bufA, N);
    k_gather2<<<(N + 3) / 4, 256, 0, stream>>>(bufA, row_ptr, edge_src, edge_nrm, dinv, bmu, bls, out, N);
}

// Round 3
// 289.467 us; speedup vs baseline: 1.8245x; 1.0725x over previous
//
#include <hip/hip_runtime.h>
#include <math.h>

// ---------------------------------------------------------------------------
// VariationalGCNEncoder: N=50000, E=800000, 128 -> 64 -> {32,32}
// R3: CSR gather with lane-preloaded packed edge metadata (int2{src,normbits})
//     + 4x-unrolled gather loads (MLP), gemm2 fused into gather1 via in-wave
//     shuffle-dot against LDS-staged [W_mu|W_ls].
// Pipeline:
//   counts -> scan -> row_ptr/cursor/dinv -> fill packed edges
//   h_pre = x @ W1                                   (gemm1)
//   t2    = ( relu(A_norm . h_pre + b1) ) @ [Wmu|Wls]  (gather1_fused)
//   out   = A_norm . t2 + [b_mu|b_ls]                (gather2)
// ---------------------------------------------------------------------------

__global__ void k_zero(int* __restrict__ p, int n) {
    int i = blockIdx.x * blockDim.x + threadIdx.x;
    if (i < n) p[i] = 0;
}

__global__ void k_count(const int* __restrict__ dst, int* __restrict__ counts, int E) {
    int i = blockIdx.x * blockDim.x + threadIdx.x;
    if (i < E) atomicAdd(&counts[dst[i]], 1);
}

// pass 1: per-block exclusive scan of counts -> row_ptr, block sums -> bsum
__global__ __launch_bounds__(256) void k_scan1(const int* __restrict__ counts,
                                               int* __restrict__ row_ptr,
                                               int* __restrict__ bsum, int N) {
    __shared__ int s[256];
    int t = threadIdx.x, i = blockIdx.x * 256 + t;
    int v = (i < N) ? counts[i] : 0;
    s[t] = v;
    __syncthreads();
    #pragma unroll
    for (int off = 1; off < 256; off <<= 1) {
        int x = (t >= off) ? s[t - off] : 0;
        __syncthreads();
        s[t] += x;
        __syncthreads();
    }
    if (i < N) row_ptr[i] = s[t] - v;           // exclusive
    if (t == 255) bsum[blockIdx.x] = s[255];    // block total
}

// pass 2: single block scans block sums (exclusive, in place). nb <= 256
__global__ __launch_bounds__(256) void k_scan2(int* __restrict__ bsum, int nb) {
    __shared__ int s[256];
    int t = threadIdx.x;
    int v = (t < nb) ? bsum[t] : 0;
    s[t] = v;
    __syncthreads();
    #pragma unroll
    for (int off = 1; off < 256; off <<= 1) {
        int x = (t >= off) ? s[t - off] : 0;
        __syncthreads();
        s[t] += x;
        __syncthreads();
    }
    if (t < nb) bsum[t] = s[t] - v;             // exclusive
}

// pass 3: add block offsets; init cursor + dinv; set row_ptr[N]=E
__global__ void k_scan3(int* __restrict__ row_ptr, const int* __restrict__ bsum,
                        const int* __restrict__ counts, int* __restrict__ cursor,
                        float* __restrict__ dinv, int N, int E) {
    int i = blockIdx.x * blockDim.x + threadIdx.x;
    if (i < N) {
        int r = row_ptr[i] + bsum[i >> 8];
        row_ptr[i] = r;
        cursor[i] = r;
        dinv[i] = rsqrtf((float)(counts[i] + 1));
    }
    if (i == 0) row_ptr[N] = E;
}

// packed edge record: .x = src node, .y = float bits of norm
__global__ void k_fill(const int* __restrict__ src, const int* __restrict__ dst,
                       const float* __restrict__ dinv, int* __restrict__ cursor,
                       int2* __restrict__ edges, int E) {
    int e = blockIdx.x * blockDim.x + threadIdx.x;
    if (e >= E) return;
    int s = src[e], d = dst[e];
    int pos = atomicAdd(&cursor[d], 1);
    edges[pos] = make_int2(s, __float_as_int(dinv[s] * dinv[d]));
}

// h_pre[N,64] = x[N,128] @ W1[128,64]
__global__ __launch_bounds__(256) void k_gemm1(const float* __restrict__ x,
                                               const float* __restrict__ W,
                                               float* __restrict__ h, int N) {
    __shared__ float xs[32][128];   // 16 KB
    __shared__ float ws[128][64];   // 32 KB
    const int tid = threadIdx.x;
    {   // stage W1 (8192 floats = 2048 float4)
        const float4* W4 = (const float4*)W;
        float4* s4 = (float4*)&ws[0][0];
        #pragma unroll
        for (int i = 0; i < 8; ++i) s4[tid + 256 * i] = W4[tid + 256 * i];
    }
    const int row0 = blockIdx.x * 32;
    {   // stage x tile (32 rows x 128 = 1024 float4)
        const float4* x4 = (const float4*)x;
        float4* s4 = (float4*)&xs[0][0];
        #pragma unroll
        for (int i = 0; i < 4; ++i) {
            int idx = tid + 256 * i;
            int r = idx >> 5, c = idx & 31;
            float4 v = make_float4(0.f, 0.f, 0.f, 0.f);
            if (row0 + r < N) v = x4[(size_t)(row0 + r) * 32 + c];
            s4[idx] = v;
        }
    }
    __syncthreads();
    const int col = tid & 63;
    const int rg  = tid >> 6;
    float acc[8] = {0, 0, 0, 0, 0, 0, 0, 0};
    for (int k = 0; k < 128; ++k) {
        float w = ws[k][col];
        #pragma unroll
        for (int j = 0; j < 8; ++j) acc[j] += xs[rg * 8 + j][k] * w;
    }
    #pragma unroll
    for (int j = 0; j < 8; ++j) {
        int r = row0 + rg * 8 + j;
        if (r < N) h[(size_t)r * 64 + col] = acc[j];
    }
}

// t2[n,:] = relu( A_norm.h_pre + b1 )[n,:] @ [Wmu|Wls]
__global__ __launch_bounds__(256) void k_gather1_fused(
        const float* __restrict__ h_pre, const int* __restrict__ row_ptr,
        const int2* __restrict__ edges, const float* __restrict__ dinv,
        const float* __restrict__ b1, const float* __restrict__ Wmu,
        const float* __restrict__ Wls, float* __restrict__ t2, int N, int E) {
    __shared__ float Ws[64][64];   // 16 KB: [k][0..31]=Wmu[k,:], [k][32..63]=Wls[k,:]
    const int tid = threadIdx.x;
    #pragma unroll
    for (int i = 0; i < 8; ++i) {
        int idx = tid + 256 * i;            // 0..2047
        int k = idx >> 5, j = idx & 31;
        Ws[k][j]      = Wmu[idx];
        Ws[k][j + 32] = Wls[idx];
    }
    __syncthreads();
    const int lane = tid & 63;
    const int n = blockIdx.x * 4 + (tid >> 6);
    if (n >= N) return;
    const int beg = row_ptr[n], end = row_ptr[n + 1];
    const float dv = dinv[n];
    float acc = dv * dv * h_pre[(size_t)n * 64 + lane] + b1[lane];
    for (int base = beg; base < end; base += 64) {
        int cnt = end - base; if (cnt > 64) cnt = 64;
        int2 m = edges[min(base + lane, E - 1)];   // coalesced preload, 1 load/chunk
        int   ms = m.x;
        float mw = __int_as_float(m.y);
        int j = 0;
        for (; j + 4 <= cnt; j += 4) {
            int   s0 = __shfl(ms, j),     s1 = __shfl(ms, j + 1);
            int   s2 = __shfl(ms, j + 2), s3 = __shfl(ms, j + 3);
            float w0 = __shfl(mw, j),     w1 = __shfl(mw, j + 1);
            float w2 = __shfl(mw, j + 2), w3 = __shfl(mw, j + 3);
            float v0 = h_pre[(size_t)s0 * 64 + lane];
            float v1 = h_pre[(size_t)s1 * 64 + lane];
            float v2 = h_pre[(size_t)s2 * 64 + lane];
            float v3 = h_pre[(size_t)s3 * 64 + lane];
            acc = fmaf(w0, v0, acc); acc = fmaf(w1, v1, acc);
            acc = fmaf(w2, v2, acc); acc = fmaf(w3, v3, acc);
        }
        for (; j < cnt; ++j) {
            int   s0 = __shfl(ms, j);
            float w0 = __shfl(mw, j);
            acc = fmaf(w0, h_pre[(size_t)s0 * 64 + lane], acc);
        }
    }
    const float hrow = fmaxf(acc, 0.f);          // relu'd h[n,lane], lives in lane
    // t2[n,lane] = sum_k hrow[k] * Ws[k][lane]  (in-wave shuffle-dot)
    float acc2 = 0.f;
    #pragma unroll
    for (int k = 0; k < 64; ++k)
        acc2 = fmaf(__shfl(hrow, k), Ws[k][lane], acc2);
    t2[(size_t)n * 64 + lane] = acc2;
}

// out: mu[n,f] (lane<32) / logstd[n,f] (lane>=32) = A_norm.t2 + self + bias
__global__ __launch_bounds__(256) void k_gather2(
        const float* __restrict__ t2, const int* __restrict__ row_ptr,
        const int2* __restrict__ edges, const float* __restrict__ dinv,
        const float* __restrict__ bmu, const float* __restrict__ bls,
        float* __restrict__ out, int N, int E) {
    const int lane = threadIdx.x & 63;
    const int n = blockIdx.x * 4 + (threadIdx.x >> 6);
    if (n >= N) return;
    const int beg = row_ptr[n], end = row_ptr[n + 1];
    const float dv = dinv[n];
    const float bias = (lane < 32) ? bmu[lane] : bls[lane - 32];
    float acc = dv * dv * t2[(size_t)n * 64 + lane] + bias;
    for (int base = beg; base < end; base += 64) {
        int cnt = end - base; if (cnt > 64) cnt = 64;
        int2 m = edges[min(base + lane, E - 1)];
        int   ms = m.x;
        float mw = __int_as_float(m.y);
        int j = 0;
        for (; j + 4 <= cnt; j += 4) {
            int   s0 = __shfl(ms, j),     s1 = __shfl(ms, j + 1);
            int   s2 = __shfl(ms, j + 2), s3 = __shfl(ms, j + 3);
            float w0 = __shfl(mw, j),     w1 = __shfl(mw, j + 1);
            float w2 = __shfl(mw, j + 2), w3 = __shfl(mw, j + 3);
            float v0 = t2[(size_t)s0 * 64 + lane];
            float v1 = t2[(size_t)s1 * 64 + lane];
            float v2 = t2[(size_t)s2 * 64 + lane];
            float v3 = t2[(size_t)s3 * 64 + lane];
            acc = fmaf(w0, v0, acc); acc = fmaf(w1, v1, acc);
            acc = fmaf(w2, v2, acc); acc = fmaf(w3, v3, acc);
        }
        for (; j < cnt; ++j) {
            int   s0 = __shfl(ms, j);
            float w0 = __shfl(mw, j);
            acc = fmaf(w0, t2[(size_t)s0 * 64 + lane], acc);
        }
    }
    if (lane < 32) out[(size_t)n * 32 + lane] = acc;
    else           out[(size_t)N * 32 + (size_t)n * 32 + (lane - 32)] = acc;
}

extern "C" void kernel_launch(void* const* d_in, const int* in_sizes, int n_in,
                              void* d_out, int out_size, void* d_ws, size_t ws_size,
                              hipStream_t stream) {
    const float* x   = (const float*)d_in[0];
    const int*   ei  = (const int*)d_in[1];
    const float* W1  = (const float*)d_in[2];
    const float* b1  = (const float*)d_in[3];
    const float* Wmu = (const float*)d_in[4];
    const float* bmu = (const float*)d_in[5];
    const float* Wls = (const float*)d_in[6];
    const float* bls = (const float*)d_in[7];
    float* out = (float*)d_out;

    const int N = in_sizes[0] / 128;          // 50000
    const int E = in_sizes[1] / 2;            // 800000
    const int* src = ei;
    const int* dst = ei + E;
    const int NB = (N + 255) / 256;           // 196 scan blocks

    char* w = (char*)d_ws;
    auto carve = [&](size_t bytes) { char* p = w; w += (bytes + 1023) & ~(size_t)1023; return p; };
    int*   counts   = (int*)  carve((size_t)N * 4);
    int*   row_ptr  = (int*)  carve((size_t)(N + 1) * 4);
    int*   cursor   = (int*)  carve((size_t)N * 4);
    int*   bsum     = (int*)  carve(256 * 4);
    float* dinv     = (float*)carve((size_t)N * 4);
    int2*  edges    = (int2*) carve((size_t)E * 8);
    float* bufA     = (float*)carve((size_t)N * 64 * 4);   // h_pre
    float* bufB     = (float*)carve((size_t)N * 64 * 4);   // t2

    k_zero   <<<NB, 256, 0, stream>>>(counts, N);
    k_count  <<<(E + 255) / 256, 256, 0, stream>>>(dst, counts, E);
    k_scan1  <<<NB, 256, 0, stream>>>(counts, row_ptr, bsum, N);
    k_scan2  <<<1, 256, 0, stream>>>(bsum, NB);
    k_scan3  <<<NB, 256, 0, stream>>>(row_ptr, bsum, counts, cursor, dinv, N, E);
    k_fill   <<<(E + 255) / 256, 256, 0, stream>>>(src, dst, dinv, cursor, edges, E);
    k_gemm1  <<<(N + 31) / 32, 256, 0, stream>>>(x, W1, bufA, N);
    k_gather1_fused<<<(N + 3) / 4, 256, 0, stream>>>(bufA, row_ptr, edges, dinv, b1,
                                                     Wmu, Wls, bufB, N, E);
    k_gather2<<<(N + 3) / 4, 256, 0, stream>>>(bufB, row_ptr, edges, dinv, bmu, bls,
                                               out, N, E);
}

// Round 4
// 278.613 us; speedup vs baseline: 1.8956x; 1.0390x over previous
//
#include <hip/hip_runtime.h>
#include <hip/hip_fp16.h>
#include <math.h>

// ---------------------------------------------------------------------------
// VariationalGCNEncoder: N=50000, E=800000, 128 -> 64 -> {32,32}
// R4: bf16 gathered matrices (halve L2-miss traffic), 4B packed edges
//     (src:u16 | norm:fp16), gemm2 eliminated via (A.h)@W == A.(h@W),
//     count fused with gemm1. Gathers are L2-miss-traffic bound (~1.6TB/s
//     ceiling observed R2/R3) -> fewer bytes is the only lever.
// Pipeline:
//   zero -> [count | gemm1(bf16 out)] -> scan x3 -> fill(packed)
//   h   = relu(A_norm . h_pre + b1)          bf16   (gather1)
//   out = (A_norm . h) @ [Wmu|Wls] + bias    f32    (gather2 + in-block dot)
// ---------------------------------------------------------------------------

typedef unsigned int uint;
typedef unsigned short ushort;

__device__ __forceinline__ ushort f2bf(float x) {          // f32 -> bf16 RNE
    uint u = __float_as_uint(x);
    u += 0x7fffu + ((u >> 16) & 1u);
    return (ushort)(u >> 16);
}
__device__ __forceinline__ float bf2f(ushort h) {          // bf16 -> f32
    return __uint_as_float((uint)h << 16);
}
__device__ __forceinline__ float unpack_norm(uint r) {     // fp16 in high 16
    return __half2float(__ushort_as_half((ushort)(r >> 16)));
}

__global__ void k_zero(int* __restrict__ p, int n) {
    int i = blockIdx.x * blockDim.x + threadIdx.x;
    if (i < n) p[i] = 0;
}

// blocks [0,GB1): gemm1 h_pre = x @ W1 (bf16 out); blocks [GB1,..): count
__global__ __launch_bounds__(256) void k_count_gemm1(
        const float* __restrict__ x, const float* __restrict__ W,
        ushort* __restrict__ h, int N, int GB1,
        const int* __restrict__ dst, int* __restrict__ counts, int E) {
    __shared__ float xs[32][128];   // 16 KB
    __shared__ float ws[128][64];   // 32 KB
    if (blockIdx.x >= GB1) {        // ---- degree count path ----
        int i = (blockIdx.x - GB1) * 256 + threadIdx.x;
        if (i < E) atomicAdd(&counts[dst[i]], 1);
        return;
    }
    const int tid = threadIdx.x;
    {   // stage W1 (8192 floats = 2048 float4)
        const float4* W4 = (const float4*)W;
        float4* s4 = (float4*)&ws[0][0];
        #pragma unroll
        for (int i = 0; i < 8; ++i) s4[tid + 256 * i] = W4[tid + 256 * i];
    }
    const int row0 = blockIdx.x * 32;
    {   // stage x tile (32 rows x 128)
        const float4* x4 = (const float4*)x;
        float4* s4 = (float4*)&xs[0][0];
        #pragma unroll
        for (int i = 0; i < 4; ++i) {
            int idx = tid + 256 * i;
            int r = idx >> 5, c = idx & 31;
            float4 v = make_float4(0.f, 0.f, 0.f, 0.f);
            if (row0 + r < N) v = x4[(size_t)(row0 + r) * 32 + c];
            s4[idx] = v;
        }
    }
    __syncthreads();
    const int col = tid & 63;
    const int rg  = tid >> 6;
    float acc[8] = {0, 0, 0, 0, 0, 0, 0, 0};
    for (int k = 0; k < 128; ++k) {
        float w = ws[k][col];
        #pragma unroll
        for (int j = 0; j < 8; ++j) acc[j] += xs[rg * 8 + j][k] * w;
    }
    #pragma unroll
    for (int j = 0; j < 8; ++j) {
        int r = row0 + rg * 8 + j;
        if (r < N) h[(size_t)r * 64 + col] = f2bf(acc[j]);
    }
}

// pass 1: per-block exclusive scan of counts -> row_ptr, block sums -> bsum
__global__ __launch_bounds__(256) void k_scan1(const int* __restrict__ counts,
                                               int* __restrict__ row_ptr,
                                               int* __restrict__ bsum, int N) {
    __shared__ int s[256];
    int t = threadIdx.x, i = blockIdx.x * 256 + t;
    int v = (i < N) ? counts[i] : 0;
    s[t] = v;
    __syncthreads();
    #pragma unroll
    for (int off = 1; off < 256; off <<= 1) {
        int x = (t >= off) ? s[t - off] : 0;
        __syncthreads();
        s[t] += x;
        __syncthreads();
    }
    if (i < N) row_ptr[i] = s[t] - v;
    if (t == 255) bsum[blockIdx.x] = s[255];
}

__global__ __launch_bounds__(256) void k_scan2(int* __restrict__ bsum, int nb) {
    __shared__ int s[256];
    int t = threadIdx.x;
    int v = (t < nb) ? bsum[t] : 0;
    s[t] = v;
    __syncthreads();
    #pragma unroll
    for (int off = 1; off < 256; off <<= 1) {
        int x = (t >= off) ? s[t - off] : 0;
        __syncthreads();
        s[t] += x;
        __syncthreads();
    }
    if (t < nb) bsum[t] = s[t] - v;
}

__global__ void k_scan3(int* __restrict__ row_ptr, const int* __restrict__ bsum,
                        const int* __restrict__ counts, int* __restrict__ cursor,
                        float* __restrict__ dinv, int N, int E) {
    int i = blockIdx.x * blockDim.x + threadIdx.x;
    if (i < N) {
        int r = row_ptr[i] + bsum[i >> 8];
        row_ptr[i] = r;
        cursor[i] = r;
        dinv[i] = rsqrtf((float)(counts[i] + 1));
    }
    if (i == 0) row_ptr[N] = E;
}

// packed edge record: low 16 = src (N < 65536), high 16 = fp16(norm)
__global__ void k_fill(const int* __restrict__ src, const int* __restrict__ dst,
                       const float* __restrict__ dinv, int* __restrict__ cursor,
                       uint* __restrict__ edges, int E) {
    int e = blockIdx.x * blockDim.x + threadIdx.x;
    if (e >= E) return;
    int s = src[e], d = dst[e];
    int pos = atomicAdd(&cursor[d], 1);
    ushort nb = __half_as_ushort(__float2half(dinv[s] * dinv[d]));
    edges[pos] = (uint)s | ((uint)nb << 16);
}

// h[n,f] = relu( dinv^2*h_pre[n,f] + b1[f] + sum norm*h_pre[src,f] )  (bf16)
__global__ __launch_bounds__(256) void k_gather1(
        const ushort* __restrict__ hp, const int* __restrict__ row_ptr,
        const uint* __restrict__ edges, const float* __restrict__ dinv,
        const float* __restrict__ b1, ushort* __restrict__ hout, int N, int E) {
    const int lane = threadIdx.x & 63;
    const int n = blockIdx.x * 4 + (threadIdx.x >> 6);
    if (n >= N) return;
    const int beg = row_ptr[n], end = row_ptr[n + 1];
    const float dv = dinv[n];
    float acc = dv * dv * bf2f(hp[(size_t)n * 64 + lane]) + b1[lane];
    for (int base = beg; base < end; base += 64) {
        int cnt = end - base; if (cnt > 64) cnt = 64;
        uint m = edges[min(base + lane, E - 1)];   // one coalesced 4B load/chunk
        int j = 0;
        for (; j + 4 <= cnt; j += 4) {
            uint r0 = __shfl(m, j),     r1 = __shfl(m, j + 1);
            uint r2 = __shfl(m, j + 2), r3 = __shfl(m, j + 3);
            float v0 = bf2f(hp[(size_t)(r0 & 0xffffu) * 64 + lane]);
            float v1 = bf2f(hp[(size_t)(r1 & 0xffffu) * 64 + lane]);
            float v2 = bf2f(hp[(size_t)(r2 & 0xffffu) * 64 + lane]);
            float v3 = bf2f(hp[(size_t)(r3 & 0xffffu) * 64 + lane]);
            acc = fmaf(unpack_norm(r0), v0, acc);
            acc = fmaf(unpack_norm(r1), v1, acc);
            acc = fmaf(unpack_norm(r2), v2, acc);
            acc = fmaf(unpack_norm(r3), v3, acc);
        }
        for (; j < cnt; ++j) {
            uint r0 = __shfl(m, j);
            acc = fmaf(unpack_norm(r0), bf2f(hp[(size_t)(r0 & 0xffffu) * 64 + lane]), acc);
        }
    }
    hout[(size_t)n * 64 + lane] = f2bf(fmaxf(acc, 0.f));
}

// g = A_norm . h  (gather, f32 acc);  out_row = g @ [Wmu|Wls] + bias
__global__ __launch_bounds__(256) void k_gather2(
        const ushort* __restrict__ h, const int* __restrict__ row_ptr,
        const uint* __restrict__ edges, const float* __restrict__ dinv,
        const float* __restrict__ Wmu, const float* __restrict__ Wls,
        const float* __restrict__ bmu, const float* __restrict__ bls,
        float* __restrict__ out, int N, int E) {
    __shared__ float Ws[64][64];   // 16 KB: [k][0..31]=Wmu, [k][32..63]=Wls
    __shared__ float hs[4][64];    // per-wave gathered row
    const int tid = threadIdx.x;
    #pragma unroll
    for (int i = 0; i < 8; ++i) {
        int idx = tid + 256 * i;
        int k = idx >> 5, j = idx & 31;
        Ws[k][j]      = Wmu[idx];
        Ws[k][j + 32] = Wls[idx];
    }
    __syncthreads();
    const int lane = tid & 63;
    const int w = tid >> 6;
    const int n = blockIdx.x * 4 + w;
    if (n >= N) return;
    const int beg = row_ptr[n], end = row_ptr[n + 1];
    const float dv = dinv[n];
    float acc = dv * dv * bf2f(h[(size_t)n * 64 + lane]);
    for (int base = beg; base < end; base += 64) {
        int cnt = end - base; if (cnt > 64) cnt = 64;
        uint m = edges[min(base + lane, E - 1)];
        int j = 0;
        for (; j + 4 <= cnt; j += 4) {
            uint r0 = __shfl(m, j),     r1 = __shfl(m, j + 1);
            uint r2 = __shfl(m, j + 2), r3 = __shfl(m, j + 3);
            float v0 = bf2f(h[(size_t)(r0 & 0xffffu) * 64 + lane]);
            float v1 = bf2f(h[(size_t)(r1 & 0xffffu) * 64 + lane]);
            float v2 = bf2f(h[(size_t)(r2 & 0xffffu) * 64 + lane]);
            float v3 = bf2f(h[(size_t)(r3 & 0xffffu) * 64 + lane]);
            acc = fmaf(unpack_norm(r0), v0, acc);
            acc = fmaf(unpack_norm(r1), v1, acc);
            acc = fmaf(unpack_norm(r2), v2, acc);
            acc = fmaf(unpack_norm(r3), v3, acc);
        }
        for (; j < cnt; ++j) {
            uint r0 = __shfl(m, j);
            acc = fmaf(unpack_norm(r0), bf2f(h[(size_t)(r0 & 0xffffu) * 64 + lane]), acc);
        }
    }
    // stage gathered row, then out[n,lane] = sum_k g[k]*Ws[k][lane]
    hs[w][lane] = acc;           // own-wave row; lgkmcnt orders write->read
    float a0 = 0.f, a1 = 0.f, a2 = 0.f, a3 = 0.f;
    #pragma unroll
    for (int k = 0; k < 64; k += 4) {
        a0 = fmaf(hs[w][k + 0], Ws[k + 0][lane], a0);   // hs: broadcast (free)
        a1 = fmaf(hs[w][k + 1], Ws[k + 1][lane], a1);   // Ws: conflict-free
        a2 = fmaf(hs[w][k + 2], Ws[k + 2][lane], a2);
        a3 = fmaf(hs[w][k + 3], Ws[k + 3][lane], a3);
    }
    float t = (a0 + a1) + (a2 + a3);
    if (lane < 32) out[(size_t)n * 32 + lane] = t + bmu[lane];
    else           out[(size_t)N * 32 + (size_t)n * 32 + (lane - 32)] = t + bls[lane - 32];
}

extern "C" void kernel_launch(void* const* d_in, const int* in_sizes, int n_in,
                              void* d_out, int out_size, void* d_ws, size_t ws_size,
                              hipStream_t stream) {
    const float* x   = (const float*)d_in[0];
    const int*   ei  = (const int*)d_in[1];
    const float* W1  = (const float*)d_in[2];
    const float* b1  = (const float*)d_in[3];
    const float* Wmu = (const float*)d_in[4];
    const float* bmu = (const float*)d_in[5];
    const float* Wls = (const float*)d_in[6];
    const float* bls = (const float*)d_in[7];
    float* out = (float*)d_out;

    const int N = in_sizes[0] / 128;          // 50000  (< 65536: u16 src pack)
    const int E = in_sizes[1] / 2;            // 800000
    const int* src = ei;
    const int* dst = ei + E;
    const int NB  = (N + 255) / 256;          // scan blocks
    const int GB1 = (N + 31) / 32;            // gemm1 blocks
    const int CB  = (E + 255) / 256;          // count/fill blocks

    char* w = (char*)d_ws;
    auto carve = [&](size_t bytes) { char* p = w; w += (bytes + 1023) & ~(size_t)1023; return p; };
    int*    counts  = (int*)   carve((size_t)N * 4);
    int*    row_ptr = (int*)   carve((size_t)(N + 1) * 4);
    int*    cursor  = (int*)   carve((size_t)N * 4);
    int*    bsum    = (int*)   carve(256 * 4);
    float*  dinv    = (float*) carve((size_t)N * 4);
    uint*   edges   = (uint*)  carve((size_t)E * 4);
    ushort* h_pre   = (ushort*)carve((size_t)N * 64 * 2);   // bf16
    ushort* h_mid   = (ushort*)carve((size_t)N * 64 * 2);   // bf16

    k_zero       <<<NB, 256, 0, stream>>>(counts, N);
    k_count_gemm1<<<GB1 + CB, 256, 0, stream>>>(x, W1, h_pre, N, GB1, dst, counts, E);
    k_scan1      <<<NB, 256, 0, stream>>>(counts, row_ptr, bsum, N);
    k_scan2      <<<1, 256, 0, stream>>>(bsum, NB);
    k_scan3      <<<NB, 256, 0, stream>>>(row_ptr, bsum, counts, cursor, dinv, N, E);
    k_fill       <<<CB, 256, 0, stream>>>(src, dst, dinv, cursor, edges, E);
    k_gather1    <<<(N + 3) / 4, 256, 0, stream>>>(h_pre, row_ptr, edges, dinv, b1, h_mid, N, E);
    k_gather2    <<<(N + 3) / 4, 256, 0, stream>>>(h_mid, row_ptr, edges, dinv, Wmu, Wls,
                                                   bmu, bls, out, N, E);
}

// Round 5
// 240.530 us; speedup vs baseline: 2.1957x; 1.1583x over previous
//
#include <hip/hip_runtime.h>
#include <hip/hip_fp16.h>
#include <math.h>

// ---------------------------------------------------------------------------
// VariationalGCNEncoder: N=50000, E=800000, 128 -> 64 -> {32,32}
// R5: gathers are LATENCY-bound (R4: 76us vs <10us BW floor; 72 VGPR ->
//     occupancy cliff). Fix: __launch_bounds__(256,8) to cap VGPR<=64,
//     8x-unrolled gather loads, no W LDS staging in gather2 (W is L1-hot,
//     read direct from global; no __syncthreads). zero->memset node,
//     scan2 folded into scan3.
// Pipeline:
//   memset(counts) -> [count | gemm1(bf16)] -> scan1 -> scan23 -> fill
//   h   = relu(A_norm . h_pre + b1)          bf16   (gather1)
//   out = (A_norm . h) @ [Wmu|Wls] + bias    f32    (gather2, fused dot)
// ---------------------------------------------------------------------------

typedef unsigned int uint;
typedef unsigned short ushort;

__device__ __forceinline__ ushort f2bf(float x) {          // f32 -> bf16 RNE
    uint u = __float_as_uint(x);
    u += 0x7fffu + ((u >> 16) & 1u);
    return (ushort)(u >> 16);
}
__device__ __forceinline__ float bf2f(ushort h) {
    return __uint_as_float((uint)h << 16);
}
__device__ __forceinline__ float unpack_norm(uint r) {     // fp16 in high 16
    return __half2float(__ushort_as_half((ushort)(r >> 16)));
}

// blocks [0,GB1): gemm1 h_pre = x @ W1 (bf16 out); blocks [GB1,..): count
__global__ __launch_bounds__(256) void k_count_gemm1(
        const float* __restrict__ x, const float* __restrict__ W,
        ushort* __restrict__ h, int N, int GB1,
        const int* __restrict__ dst, int* __restrict__ counts, int E) {
    __shared__ float xs[32][128];   // 16 KB
    __shared__ float ws[128][64];   // 32 KB
    if (blockIdx.x >= GB1) {        // ---- degree count path ----
        int i = (blockIdx.x - GB1) * 256 + threadIdx.x;
        if (i < E) atomicAdd(&counts[dst[i]], 1);
        return;
    }
    const int tid = threadIdx.x;
    {   // stage W1
        const float4* W4 = (const float4*)W;
        float4* s4 = (float4*)&ws[0][0];
        #pragma unroll
        for (int i = 0; i < 8; ++i) s4[tid + 256 * i] = W4[tid + 256 * i];
    }
    const int row0 = blockIdx.x * 32;
    {   // stage x tile
        const float4* x4 = (const float4*)x;
        float4* s4 = (float4*)&xs[0][0];
        #pragma unroll
        for (int i = 0; i < 4; ++i) {
            int idx = tid + 256 * i;
            int r = idx >> 5, c = idx & 31;
            float4 v = make_float4(0.f, 0.f, 0.f, 0.f);
            if (row0 + r < N) v = x4[(size_t)(row0 + r) * 32 + c];
            s4[idx] = v;
        }
    }
    __syncthreads();
    const int col = tid & 63;
    const int rg  = tid >> 6;
    float acc[8] = {0, 0, 0, 0, 0, 0, 0, 0};
    for (int k = 0; k < 128; ++k) {
        float w = ws[k][col];
        #pragma unroll
        for (int j = 0; j < 8; ++j) acc[j] += xs[rg * 8 + j][k] * w;
    }
    #pragma unroll
    for (int j = 0; j < 8; ++j) {
        int r = row0 + rg * 8 + j;
        if (r < N) h[(size_t)r * 64 + col] = f2bf(acc[j]);
    }
}

// per-block exclusive scan of counts -> row_ptr, block sums -> bsum
__global__ __launch_bounds__(256) void k_scan1(const int* __restrict__ counts,
                                               int* __restrict__ row_ptr,
                                               int* __restrict__ bsum, int N) {
    __shared__ int s[256];
    int t = threadIdx.x, i = blockIdx.x * 256 + t;
    int v = (i < N) ? counts[i] : 0;
    s[t] = v;
    __syncthreads();
    #pragma unroll
    for (int off = 1; off < 256; off <<= 1) {
        int x = (t >= off) ? s[t - off] : 0;
        __syncthreads();
        s[t] += x;
        __syncthreads();
    }
    if (i < N) row_ptr[i] = s[t] - v;
    if (t == 255) bsum[blockIdx.x] = s[255];
}

// fused scan2+scan3: each block reduces bsum[0..blockIdx.x-1] itself (NB<=256),
// then applies offset, inits cursor + dinv. row_ptr[N]=E from block 0.
__global__ __launch_bounds__(256) void k_scan23(
        int* __restrict__ row_ptr, const int* __restrict__ bsum,
        const int* __restrict__ counts, int* __restrict__ cursor,
        float* __restrict__ dinv, int N, int E, int NB) {
    __shared__ int s[256];
    const int t = threadIdx.x;
    s[t] = (t < blockIdx.x && t < NB) ? bsum[t] : 0;
    __syncthreads();
    #pragma unroll
    for (int off = 128; off >= 1; off >>= 1) {
        if (t < off) s[t] += s[t + off];
        __syncthreads();
    }
    const int offset = s[0];
    const int i = blockIdx.x * 256 + t;
    if (i < N) {
        int r = row_ptr[i] + offset;
        row_ptr[i] = r;
        cursor[i] = r;
        dinv[i] = rsqrtf((float)(counts[i] + 1));
    }
    if (blockIdx.x == 0 && t == 0) row_ptr[N] = E;
}

// packed edge record: low 16 = src (N < 65536), high 16 = fp16(norm)
__global__ void k_fill(const int* __restrict__ src, const int* __restrict__ dst,
                       const float* __restrict__ dinv, int* __restrict__ cursor,
                       uint* __restrict__ edges, int E) {
    int e = blockIdx.x * blockDim.x + threadIdx.x;
    if (e >= E) return;
    int s = src[e], d = dst[e];
    int pos = atomicAdd(&cursor[d], 1);
    ushort nb = __half_as_ushort(__float2half(dinv[s] * dinv[d]));
    edges[pos] = (uint)s | ((uint)nb << 16);
}

// h[n,f] = relu( dinv^2*h_pre[n,f] + b1[f] + sum norm*h_pre[src,f] )  (bf16)
__global__ __launch_bounds__(256, 8) void k_gather1(
        const ushort* __restrict__ hp, const int* __restrict__ row_ptr,
        const uint* __restrict__ edges, const float* __restrict__ dinv,
        const float* __restrict__ b1, ushort* __restrict__ hout, int N, int E) {
    const int lane = threadIdx.x & 63;
    const int n = blockIdx.x * 4 + (threadIdx.x >> 6);
    if (n >= N) return;
    const int beg = row_ptr[n], end = row_ptr[n + 1];
    const float dv = dinv[n];
    float acc = dv * dv * bf2f(hp[(size_t)n * 64 + lane]) + b1[lane];
    for (int base = beg; base < end; base += 64) {
        int cnt = end - base; if (cnt > 64) cnt = 64;
        uint m = edges[min(base + lane, E - 1)];   // one coalesced 4B load/chunk
        int j = 0;
        for (; j + 8 <= cnt; j += 8) {             // 8 gathers in flight
            uint r0 = __shfl(m, j),     r1 = __shfl(m, j + 1);
            uint r2 = __shfl(m, j + 2), r3 = __shfl(m, j + 3);
            uint r4 = __shfl(m, j + 4), r5 = __shfl(m, j + 5);
            uint r6 = __shfl(m, j + 6), r7 = __shfl(m, j + 7);
            float v0 = bf2f(hp[(size_t)(r0 & 0xffffu) * 64 + lane]);
            float v1 = bf2f(hp[(size_t)(r1 & 0xffffu) * 64 + lane]);
            float v2 = bf2f(hp[(size_t)(r2 & 0xffffu) * 64 + lane]);
            float v3 = bf2f(hp[(size_t)(r3 & 0xffffu) * 64 + lane]);
            float v4 = bf2f(hp[(size_t)(r4 & 0xffffu) * 64 + lane]);
            float v5 = bf2f(hp[(size_t)(r5 & 0xffffu) * 64 + lane]);
            float v6 = bf2f(hp[(size_t)(r6 & 0xffffu) * 64 + lane]);
            float v7 = bf2f(hp[(size_t)(r7 & 0xffffu) * 64 + lane]);
            acc = fmaf(unpack_norm(r0), v0, acc); acc = fmaf(unpack_norm(r1), v1, acc);
            acc = fmaf(unpack_norm(r2), v2, acc); acc = fmaf(unpack_norm(r3), v3, acc);
            acc = fmaf(unpack_norm(r4), v4, acc); acc = fmaf(unpack_norm(r5), v5, acc);
            acc = fmaf(unpack_norm(r6), v6, acc); acc = fmaf(unpack_norm(r7), v7, acc);
        }
        for (; j + 4 <= cnt; j += 4) {
            uint r0 = __shfl(m, j),     r1 = __shfl(m, j + 1);
            uint r2 = __shfl(m, j + 2), r3 = __shfl(m, j + 3);
            float v0 = bf2f(hp[(size_t)(r0 & 0xffffu) * 64 + lane]);
            float v1 = bf2f(hp[(size_t)(r1 & 0xffffu) * 64 + lane]);
            float v2 = bf2f(hp[(size_t)(r2 & 0xffffu) * 64 + lane]);
            float v3 = bf2f(hp[(size_t)(r3 & 0xffffu) * 64 + lane]);
            acc = fmaf(unpack_norm(r0), v0, acc); acc = fmaf(unpack_norm(r1), v1, acc);
            acc = fmaf(unpack_norm(r2), v2, acc); acc = fmaf(unpack_norm(r3), v3, acc);
        }
        for (; j < cnt; ++j) {
            uint r0 = __shfl(m, j);
            acc = fmaf(unpack_norm(r0), bf2f(hp[(size_t)(r0 & 0xffffu) * 64 + lane]), acc);
        }
    }
    hout[(size_t)n * 64 + lane] = f2bf(fmaxf(acc, 0.f));
}

// g = A_norm . h  (gather);  out[n,lane] = sum_k g[k]*W[k*32+col] + bias
// W read straight from global (16 KB, L1-hot). No __syncthreads anywhere.
__global__ __launch_bounds__(256, 8) void k_gather2(
        const ushort* __restrict__ h, const int* __restrict__ row_ptr,
        const uint* __restrict__ edges, const float* __restrict__ dinv,
        const float* __restrict__ Wmu, const float* __restrict__ Wls,
        const float* __restrict__ bmu, const float* __restrict__ bls,
        float* __restrict__ out, int N, int E) {
    __shared__ float hs[4][64];    // per-wave gathered row (1 KB)
    const int lane = threadIdx.x & 63;
    const int w = threadIdx.x >> 6;
    const int n = blockIdx.x * 4 + w;
    if (n >= N) return;
    const int beg = row_ptr[n], end = row_ptr[n + 1];
    const float dv = dinv[n];
    float acc = dv * dv * bf2f(h[(size_t)n * 64 + lane]);
    for (int base = beg; base < end; base += 64) {
        int cnt = end - base; if (cnt > 64) cnt = 64;
        uint m = edges[min(base + lane, E - 1)];
        int j = 0;
        for (; j + 8 <= cnt; j += 8) {
            uint r0 = __shfl(m, j),     r1 = __shfl(m, j + 1);
            uint r2 = __shfl(m, j + 2), r3 = __shfl(m, j + 3);
            uint r4 = __shfl(m, j + 4), r5 = __shfl(m, j + 5);
            uint r6 = __shfl(m, j + 6), r7 = __shfl(m, j + 7);
            float v0 = bf2f(h[(size_t)(r0 & 0xffffu) * 64 + lane]);
            float v1 = bf2f(h[(size_t)(r1 & 0xffffu) * 64 + lane]);
            float v2 = bf2f(h[(size_t)(r2 & 0xffffu) * 64 + lane]);
            float v3 = bf2f(h[(size_t)(r3 & 0xffffu) * 64 + lane]);
            float v4 = bf2f(h[(size_t)(r4 & 0xffffu) * 64 + lane]);
            float v5 = bf2f(h[(size_t)(r5 & 0xffffu) * 64 + lane]);
            float v6 = bf2f(h[(size_t)(r6 & 0xffffu) * 64 + lane]);
            float v7 = bf2f(h[(size_t)(r7 & 0xffffu) * 64 + lane]);
            acc = fmaf(unpack_norm(r0), v0, acc); acc = fmaf(unpack_norm(r1), v1, acc);
            acc = fmaf(unpack_norm(r2), v2, acc); acc = fmaf(unpack_norm(r3), v3, acc);
            acc = fmaf(unpack_norm(r4), v4, acc); acc = fmaf(unpack_norm(r5), v5, acc);
            acc = fmaf(unpack_norm(r6), v6, acc); acc = fmaf(unpack_norm(r7), v7, acc);
        }
        for (; j + 4 <= cnt; j += 4) {
            uint r0 = __shfl(m, j),     r1 = __shfl(m, j + 1);
            uint r2 = __shfl(m, j + 2), r3 = __shfl(m, j + 3);
            float v0 = bf2f(h[(size_t)(r0 & 0xffffu) * 64 + lane]);
            float v1 = bf2f(h[(size_t)(r1 & 0xffffu) * 64 + lane]);
            float v2 = bf2f(h[(size_t)(r2 & 0xffffu) * 64 + lane]);
            float v3 = bf2f(h[(size_t)(r3 & 0xffffu) * 64 + lane]);
            acc = fmaf(unpack_norm(r0), v0, acc); acc = fmaf(unpack_norm(r1), v1, acc);
            acc = fmaf(unpack_norm(r2), v2, acc); acc = fmaf(unpack_norm(r3), v3, acc);
        }
        for (; j < cnt; ++j) {
            uint r0 = __shfl(m, j);
            acc = fmaf(unpack_norm(r0), bf2f(h[(size_t)(r0 & 0xffffu) * 64 + lane]), acc);
        }
    }
    // epilogue: out_row = g @ [Wmu|Wls] + bias ; W from global (L1-hot)
    hs[w][lane] = acc;                         // own-wave slab; lgkmcnt ordered
    const float* Wsel = (lane < 32) ? (Wmu + lane) : (Wls + (lane - 32));
    const float bias  = (lane < 32) ? bmu[lane] : bls[lane - 32];
    float a0 = 0.f, a1 = 0.f, a2 = 0.f, a3 = 0.f;
    #pragma unroll 4
    for (int k = 0; k < 64; k += 4) {
        a0 = fmaf(hs[w][k + 0], Wsel[(k + 0) * 32], a0);
        a1 = fmaf(hs[w][k + 1], Wsel[(k + 1) * 32], a1);
        a2 = fmaf(hs[w][k + 2], Wsel[(k + 2) * 32], a2);
        a3 = fmaf(hs[w][k + 3], Wsel[(k + 3) * 32], a3);
    }
    float t = (a0 + a1) + (a2 + a3) + bias;
    if (lane < 32) out[(size_t)n * 32 + lane] = t;
    else           out[(size_t)N * 32 + (size_t)n * 32 + (lane - 32)] = t;
}

extern "C" void kernel_launch(void* const* d_in, const int* in_sizes, int n_in,
                              void* d_out, int out_size, void* d_ws, size_t ws_size,
                              hipStream_t stream) {
    const float* x   = (const float*)d_in[0];
    const int*   ei  = (const int*)d_in[1];
    const float* W1  = (const float*)d_in[2];
    const float* b1  = (const float*)d_in[3];
    const float* Wmu = (const float*)d_in[4];
    const float* bmu = (const float*)d_in[5];
    const float* Wls = (const float*)d_in[6];
    const float* bls = (const float*)d_in[7];
    float* out = (float*)d_out;

    const int N = in_sizes[0] / 128;          // 50000  (< 65536: u16 src pack)
    const int E = in_sizes[1] / 2;            // 800000
    const int* src = ei;
    const int* dst = ei + E;
    const int NB  = (N + 255) / 256;          // scan blocks (196 <= 256)
    const int GB1 = (N + 31) / 32;            // gemm1 blocks
    const int CB  = (E + 255) / 256;          // count/fill blocks

    char* w = (char*)d_ws;
    auto carve = [&](size_t bytes) { char* p = w; w += (bytes + 1023) & ~(size_t)1023; return p; };
    int*    counts  = (int*)   carve((size_t)N * 4);
    int*    row_ptr = (int*)   carve((size_t)(N + 1) * 4);
    int*    cursor  = (int*)   carve((size_t)N * 4);
    int*    bsum    = (int*)   carve(256 * 4);
    float*  dinv    = (float*) carve((size_t)N * 4);
    uint*   edges   = (uint*)  carve((size_t)E * 4);
    ushort* h_pre   = (ushort*)carve((size_t)N * 64 * 2);   // bf16
    ushort* h_mid   = (ushort*)carve((size_t)N * 64 * 2);   // bf16

    hipMemsetAsync(counts, 0, (size_t)N * 4, stream);
    k_count_gemm1<<<GB1 + CB, 256, 0, stream>>>(x, W1, h_pre, N, GB1, dst, counts, E);
    k_scan1      <<<NB, 256, 0, stream>>>(counts, row_ptr, bsum, N);
    k_scan23     <<<NB, 256, 0, stream>>>(row_ptr, bsum, counts, cursor, dinv, N, E, NB);
    k_fill       <<<CB, 256, 0, stream>>>(src, dst, dinv, cursor, edges, E);
    k_gather1    <<<(N + 3) / 4, 256, 0, stream>>>(h_pre, row_ptr, edges, dinv, b1, h_mid, N, E);
    k_gather2    <<<(N + 3) / 4, 256, 0, stream>>>(h_mid, row_ptr, edges, dinv, Wmu, Wls,
                                                   bmu, bls, out, N, E);
}

// Round 6
// 236.154 us; speedup vs baseline: 2.2364x; 1.0185x over previous
//
#include <hip/hip_runtime.h>
#include <hip/hip_fp16.h>
#include <math.h>

// ---------------------------------------------------------------------------
// VariationalGCNEncoder: N=50000, E=800000, 128 -> 64 -> {32,32}
// R6: gemm1 rewritten as LDS-free MFMA (bf16 16x16x32), fed by a prep kernel
//     that fuses [degree count | x->bf16 convert | W1->bf16 transpose] (all
//     LDS-free: no occupancy interference, unlike R5's 48KB-LDS fusion).
//     gemm fused with k_fill (both low-VGPR, LDS-free). Gathers kept from R5.
// Pipeline:
//   memset(counts)
//   prep:      [count | xbf = bf16(x) | wtbf = bf16(W1^T)]
//   scan1, scan23
//   fill_gemm: [fill packed edges | h_pre = xbf @ W1  (MFMA, bf16 out)]
//   gather1:   h = relu(A_norm . h_pre + b1)            (bf16)
//   gather2:   out = (A_norm . h) @ [Wmu|Wls] + bias    (f32)
// MFMA layouts (verified, guide §3/m89/m120):
//   A[m=lane&15][k=(lane>>4)*8+j], B[k=(lane>>4)*8+j][n=lane&15],
//   D: col=lane&15, row=(lane>>4)*4+reg.
// ---------------------------------------------------------------------------

typedef unsigned int uint;
typedef unsigned short ushort;
typedef __attribute__((ext_vector_type(8))) short short8;   // 8 bf16 = 4 VGPR
typedef __attribute__((ext_vector_type(4))) float f32x4;    // MFMA acc

__device__ __forceinline__ ushort f2bf(float x) {          // f32 -> bf16 RNE
    uint u = __float_as_uint(x);
    u += 0x7fffu + ((u >> 16) & 1u);
    return (ushort)(u >> 16);
}
__device__ __forceinline__ float bf2f(ushort h) {
    return __uint_as_float((uint)h << 16);
}
__device__ __forceinline__ float unpack_norm(uint r) {     // fp16 in high 16
    return __half2float(__ushort_as_half((ushort)(r >> 16)));
}

// blocks [0,CB): degree count; [CB,CB+XB): x->bf16; [CB+XB]: W1 -> wtbf[n][k]
__global__ __launch_bounds__(256) void k_prep(
        const int* __restrict__ dst, int* __restrict__ counts, int E, int CB,
        const float* __restrict__ x, ushort* __restrict__ xbf, int nx4, int XB,
        const float* __restrict__ W1, ushort* __restrict__ wtbf) {
    const int tid = threadIdx.x;
    const int b = blockIdx.x;
    if (b < CB) {                                  // ---- degree count ----
        int i = b * 256 + tid;
        if (i < E) atomicAdd(&counts[dst[i]], 1);
    } else if (b < CB + XB) {                      // ---- x -> bf16 ----
        int i = (b - CB) * 256 + tid;              // float4 index
        if (i < nx4) {
            float4 v = ((const float4*)x)[i];
            uint2 p;
            p.x = (uint)f2bf(v.x) | ((uint)f2bf(v.y) << 16);
            p.y = (uint)f2bf(v.z) | ((uint)f2bf(v.w) << 16);
            ((uint2*)xbf)[i] = p;
        }
    } else {                                       // ---- W1^T -> bf16 ----
        for (int i = tid; i < 128 * 64; i += 256) {
            int k = i >> 6, n = i & 63;            // W1[k][n], coalesced read
            wtbf[n * 128 + k] = f2bf(W1[i]);
        }
    }
}

// per-block exclusive scan of counts -> row_ptr, block sums -> bsum
__global__ __launch_bounds__(256) void k_scan1(const int* __restrict__ counts,
                                               int* __restrict__ row_ptr,
                                               int* __restrict__ bsum, int N) {
    __shared__ int s[256];
    int t = threadIdx.x, i = blockIdx.x * 256 + t;
    int v = (i < N) ? counts[i] : 0;
    s[t] = v;
    __syncthreads();
    #pragma unroll
    for (int off = 1; off < 256; off <<= 1) {
        int x = (t >= off) ? s[t - off] : 0;
        __syncthreads();
        s[t] += x;
        __syncthreads();
    }
    if (i < N) row_ptr[i] = s[t] - v;
    if (t == 255) bsum[blockIdx.x] = s[255];
}

// fused scan2+scan3 (NB<=256): block reduces its bsum prefix, applies offset,
// inits cursor + dinv; row_ptr[N]=E from block 0.
__global__ __launch_bounds__(256) void k_scan23(
        int* __restrict__ row_ptr, const int* __restrict__ bsum,
        const int* __restrict__ counts, int* __restrict__ cursor,
        float* __restrict__ dinv, int N, int E, int NB) {
    __shared__ int s[256];
    const int t = threadIdx.x;
    s[t] = (t < blockIdx.x && t < NB) ? bsum[t] : 0;
    __syncthreads();
    #pragma unroll
    for (int off = 128; off >= 1; off >>= 1) {
        if (t < off) s[t] += s[t + off];
        __syncthreads();
    }
    const int offset = s[0];
    const int i = blockIdx.x * 256 + t;
    if (i < N) {
        int r = row_ptr[i] + offset;
        row_ptr[i] = r;
        cursor[i] = r;
        dinv[i] = rsqrtf((float)(counts[i] + 1));
    }
    if (blockIdx.x == 0 && t == 0) row_ptr[N] = E;
}

// blocks [0,FB): fill packed edges; [FB,..): MFMA gemm h_pre = xbf @ W1 (bf16)
__global__ __launch_bounds__(256, 6) void k_fill_gemm(
        const int* __restrict__ src, const int* __restrict__ dst,
        const float* __restrict__ dinv, int* __restrict__ cursor,
        uint* __restrict__ edges, int E, int FB,
        const ushort* __restrict__ xbf, const ushort* __restrict__ wtbf,
        ushort* __restrict__ h_pre, int N) {
    const int tid = threadIdx.x;
    if (blockIdx.x < FB) {                         // ---- CSR fill ----
        int e = blockIdx.x * 256 + tid;
        if (e >= E) return;
        int s = src[e], d = dst[e];
        int pos = atomicAdd(&cursor[d], 1);
        ushort nb = __half_as_ushort(__float2half(dinv[s] * dinv[d]));
        edges[pos] = (uint)s | ((uint)nb << 16);
        return;
    }
    // ---- MFMA gemm: wave computes 16 rows x 64 cols, k=128 in 4 chunks ----
    const int bid = blockIdx.x - FB;
    const int w = tid >> 6, l = tid & 63;
    const int m = l & 15, q = l >> 4;              // q = quad (0..3)
    const int row0 = bid * 64 + w * 16;
    const size_t arow = (size_t)min(row0 + m, N - 1);   // clamp; store guarded
    f32x4 acc0 = {0.f, 0.f, 0.f, 0.f}, acc1 = acc0, acc2 = acc0, acc3 = acc0;
    #pragma unroll
    for (int kc = 0; kc < 4; ++kc) {
        const int kofs = kc * 32 + q * 8;
        short8 a = *(const short8*)(xbf + arow * 128 + kofs);     // A[m][k..k+7]
        short8 b0 = *(const short8*)(wtbf + (size_t)(0 * 16 + m) * 128 + kofs);
        short8 b1 = *(const short8*)(wtbf + (size_t)(1 * 16 + m) * 128 + kofs);
        short8 b2 = *(const short8*)(wtbf + (size_t)(2 * 16 + m) * 128 + kofs);
        short8 b3 = *(const short8*)(wtbf + (size_t)(3 * 16 + m) * 128 + kofs);
        acc0 = __builtin_amdgcn_mfma_f32_16x16x32_bf16(a, b0, acc0, 0, 0, 0);
        acc1 = __builtin_amdgcn_mfma_f32_16x16x32_bf16(a, b1, acc1, 0, 0, 0);
        acc2 = __builtin_amdgcn_mfma_f32_16x16x32_bf16(a, b2, acc2, 0, 0, 0);
        acc3 = __builtin_amdgcn_mfma_f32_16x16x32_bf16(a, b3, acc3, 0, 0, 0);
    }
    #pragma unroll
    for (int r = 0; r < 4; ++r) {                  // D row = q*4+r, col = g*16+m
        int row = row0 + q * 4 + r;
        if (row >= N) continue;
        ushort* hr = h_pre + (size_t)row * 64 + m;
        hr[0]  = f2bf(acc0[r]);
        hr[16] = f2bf(acc1[r]);
        hr[32] = f2bf(acc2[r]);
        hr[48] = f2bf(acc3[r]);
    }
}

// h[n,f] = relu( dinv^2*h_pre[n,f] + b1[f] + sum norm*h_pre[src,f] )  (bf16)
__global__ __launch_bounds__(256, 8) void k_gather1(
        const ushort* __restrict__ hp, const int* __restrict__ row_ptr,
        const uint* __restrict__ edges, const float* __restrict__ dinv,
        const float* __restrict__ b1, ushort* __restrict__ hout, int N, int E) {
    const int lane = threadIdx.x & 63;
    const int n = blockIdx.x * 4 + (threadIdx.x >> 6);
    if (n >= N) return;
    const int beg = row_ptr[n], end = row_ptr[n + 1];
    const float dv = dinv[n];
    float acc = dv * dv * bf2f(hp[(size_t)n * 64 + lane]) + b1[lane];
    for (int base = beg; base < end; base += 64) {
        int cnt = end - base; if (cnt > 64) cnt = 64;
        uint m = edges[min(base + lane, E - 1)];   // one coalesced 4B load/chunk
        int j = 0;
        for (; j + 8 <= cnt; j += 8) {             // 8 gathers in flight
            uint r0 = __shfl(m, j),     r1 = __shfl(m, j + 1);
            uint r2 = __shfl(m, j + 2), r3 = __shfl(m, j + 3);
            uint r4 = __shfl(m, j + 4), r5 = __shfl(m, j + 5);
            uint r6 = __shfl(m, j + 6), r7 = __shfl(m, j + 7);
            float v0 = bf2f(hp[(size_t)(r0 & 0xffffu) * 64 + lane]);
            float v1 = bf2f(hp[(size_t)(r1 & 0xffffu) * 64 + lane]);
            float v2 = bf2f(hp[(size_t)(r2 & 0xffffu) * 64 + lane]);
            float v3 = bf2f(hp[(size_t)(r3 & 0xffffu) * 64 + lane]);
            float v4 = bf2f(hp[(size_t)(r4 & 0xffffu) * 64 + lane]);
            float v5 = bf2f(hp[(size_t)(r5 & 0xffffu) * 64 + lane]);
            float v6 = bf2f(hp[(size_t)(r6 & 0xffffu) * 64 + lane]);
            float v7 = bf2f(hp[(size_t)(r7 & 0xffffu) * 64 + lane]);
            acc = fmaf(unpack_norm(r0), v0, acc); acc = fmaf(unpack_norm(r1), v1, acc);
            acc = fmaf(unpack_norm(r2), v2, acc); acc = fmaf(unpack_norm(r3), v3, acc);
            acc = fmaf(unpack_norm(r4), v4, acc); acc = fmaf(unpack_norm(r5), v5, acc);
            acc = fmaf(unpack_norm(r6), v6, acc); acc = fmaf(unpack_norm(r7), v7, acc);
        }
        for (; j + 4 <= cnt; j += 4) {
            uint r0 = __shfl(m, j),     r1 = __shfl(m, j + 1);
            uint r2 = __shfl(m, j + 2), r3 = __shfl(m, j + 3);
            float v0 = bf2f(hp[(size_t)(r0 & 0xffffu) * 64 + lane]);
            float v1 = bf2f(hp[(size_t)(r1 & 0xffffu) * 64 + lane]);
            float v2 = bf2f(hp[(size_t)(r2 & 0xffffu) * 64 + lane]);
            float v3 = bf2f(hp[(size_t)(r3 & 0xffffu) * 64 + lane]);
            acc = fmaf(unpack_norm(r0), v0, acc); acc = fmaf(unpack_norm(r1), v1, acc);
            acc = fmaf(unpack_norm(r2), v2, acc); acc = fmaf(unpack_norm(r3), v3, acc);
        }
        for (; j < cnt; ++j) {
            uint r0 = __shfl(m, j);
            acc = fmaf(unpack_norm(r0), bf2f(hp[(size_t)(r0 & 0xffffu) * 64 + lane]), acc);
        }
    }
    hout[(size_t)n * 64 + lane] = f2bf(fmaxf(acc, 0.f));
}

// g = A_norm . h  (gather);  out[n,lane] = sum_k g[k]*W[k*32+col] + bias
__global__ __launch_bounds__(256, 8) void k_gather2(
        const ushort* __restrict__ h, const int* __restrict__ row_ptr,
        const uint* __restrict__ edges, const float* __restrict__ dinv,
        const float* __restrict__ Wmu, const float* __restrict__ Wls,
        const float* __restrict__ bmu, const float* __restrict__ bls,
        float* __restrict__ out, int N, int E) {
    __shared__ float hs[4][64];    // per-wave gathered row (1 KB)
    const int lane = threadIdx.x & 63;
    const int w = threadIdx.x >> 6;
    const int n = blockIdx.x * 4 + w;
    if (n >= N) return;
    const int beg = row_ptr[n], end = row_ptr[n + 1];
    const float dv = dinv[n];
    float acc = dv * dv * bf2f(h[(size_t)n * 64 + lane]);
    for (int base = beg; base < end; base += 64) {
        int cnt = end - base; if (cnt > 64) cnt = 64;
        uint m = edges[min(base + lane, E - 1)];
        int j = 0;
        for (; j + 8 <= cnt; j += 8) {
            uint r0 = __shfl(m, j),     r1 = __shfl(m, j + 1);
            uint r2 = __shfl(m, j + 2), r3 = __shfl(m, j + 3);
            uint r4 = __shfl(m, j + 4), r5 = __shfl(m, j + 5);
            uint r6 = __shfl(m, j + 6), r7 = __shfl(m, j + 7);
            float v0 = bf2f(h[(size_t)(r0 & 0xffffu) * 64 + lane]);
            float v1 = bf2f(h[(size_t)(r1 & 0xffffu) * 64 + lane]);
            float v2 = bf2f(h[(size_t)(r2 & 0xffffu) * 64 + lane]);
            float v3 = bf2f(h[(size_t)(r3 & 0xffffu) * 64 + lane]);
            float v4 = bf2f(h[(size_t)(r4 & 0xffffu) * 64 + lane]);
            float v5 = bf2f(h[(size_t)(r5 & 0xffffu) * 64 + lane]);
            float v6 = bf2f(h[(size_t)(r6 & 0xffffu) * 64 + lane]);
            float v7 = bf2f(h[(size_t)(r7 & 0xffffu) * 64 + lane]);
            acc = fmaf(unpack_norm(r0), v0, acc); acc = fmaf(unpack_norm(r1), v1, acc);
            acc = fmaf(unpack_norm(r2), v2, acc); acc = fmaf(unpack_norm(r3), v3, acc);
            acc = fmaf(unpack_norm(r4), v4, acc); acc = fmaf(unpack_norm(r5), v5, acc);
            acc = fmaf(unpack_norm(r6), v6, acc); acc = fmaf(unpack_norm(r7), v7, acc);
        }
        for (; j + 4 <= cnt; j += 4) {
            uint r0 = __shfl(m, j),     r1 = __shfl(m, j + 1);
            uint r2 = __shfl(m, j + 2), r3 = __shfl(m, j + 3);
            float v0 = bf2f(h[(size_t)(r0 & 0xffffu) * 64 + lane]);
            float v1 = bf2f(h[(size_t)(r1 & 0xffffu) * 64 + lane]);
            float v2 = bf2f(h[(size_t)(r2 & 0xffffu) * 64 + lane]);
            float v3 = bf2f(h[(size_t)(r3 & 0xffffu) * 64 + lane]);
            acc = fmaf(unpack_norm(r0), v0, acc); acc = fmaf(unpack_norm(r1), v1, acc);
            acc = fmaf(unpack_norm(r2), v2, acc); acc = fmaf(unpack_norm(r3), v3, acc);
        }
        for (; j < cnt; ++j) {
            uint r0 = __shfl(m, j);
            acc = fmaf(unpack_norm(r0), bf2f(h[(size_t)(r0 & 0xffffu) * 64 + lane]), acc);
        }
    }
    hs[w][lane] = acc;                         // own-wave slab; lgkmcnt ordered
    const float* Wsel = (lane < 32) ? (Wmu + lane) : (Wls + (lane - 32));
    const float bias  = (lane < 32) ? bmu[lane] : bls[lane - 32];
    float a0 = 0.f, a1 = 0.f, a2 = 0.f, a3 = 0.f;
    #pragma unroll 4
    for (int k = 0; k < 64; k += 4) {
        a0 = fmaf(hs[w][k + 0], Wsel[(k + 0) * 32], a0);
        a1 = fmaf(hs[w][k + 1], Wsel[(k + 1) * 32], a1);
        a2 = fmaf(hs[w][k + 2], Wsel[(k + 2) * 32], a2);
        a3 = fmaf(hs[w][k + 3], Wsel[(k + 3) * 32], a3);
    }
    float t = (a0 + a1) + (a2 + a3) + bias;
    if (lane < 32) out[(size_t)n * 32 + lane] = t;
    else           out[(size_t)N * 32 + (size_t)n * 32 + (lane - 32)] = t;
}

extern "C" void kernel_launch(void* const* d_in, const int* in_sizes, int n_in,
                              void* d_out, int out_size, void* d_ws, size_t ws_size,
                              hipStream_t stream) {
    const float* x   = (const float*)d_in[0];
    const int*   ei  = (const int*)d_in[1];
    const float* W1  = (const float*)d_in[2];
    const float* b1  = (const float*)d_in[3];
    const float* Wmu = (const float*)d_in[4];
    const float* bmu = (const float*)d_in[5];
    const float* Wls = (const float*)d_in[6];
    const float* bls = (const float*)d_in[7];
    float* out = (float*)d_out;

    const int N = in_sizes[0] / 128;          // 50000  (< 65536: u16 src pack)
    const int E = in_sizes[1] / 2;            // 800000
    const int* src = ei;
    const int* dst = ei + E;
    const int NB  = (N + 255) / 256;          // scan blocks (196 <= 256)
    const int CB  = (E + 255) / 256;          // count / fill blocks
    const int nx4 = (N * 128) / 4;            // x as float4 count (exact)
    const int XB  = (nx4 + 255) / 256;        // x-convert blocks
    const int RB  = (N + 63) / 64;            // gemm row-tile blocks

    char* w = (char*)d_ws;
    auto carve = [&](size_t bytes) { char* p = w; w += (bytes + 1023) & ~(size_t)1023; return p; };
    int*    counts  = (int*)   carve((size_t)N * 4);
    int*    row_ptr = (int*)   carve((size_t)(N + 1) * 4);
    int*    cursor  = (int*)   carve((size_t)N * 4);
    int*    bsum    = (int*)   carve(256 * 4);
    float*  dinv    = (float*) carve((size_t)N * 4);
    uint*   edges   = (uint*)  carve((size_t)E * 4);
    ushort* xbf     = (ushort*)carve((size_t)N * 128 * 2);  // bf16 x
    ushort* wtbf    = (ushort*)carve((size_t)64 * 128 * 2); // bf16 W1^T
    ushort* h_pre   = (ushort*)carve((size_t)N * 64 * 2);   // bf16
    ushort* h_mid   = (ushort*)carve((size_t)N * 64 * 2);   // bf16

    hipMemsetAsync(counts, 0, (size_t)N * 4, stream);
    k_prep     <<<CB + XB + 1, 256, 0, stream>>>(dst, counts, E, CB,
                                                 x, xbf, nx4, XB, W1, wtbf);
    k_scan1    <<<NB, 256, 0, stream>>>(counts, row_ptr, bsum, N);
    k_scan23   <<<NB, 256, 0, stream>>>(row_ptr, bsum, counts, cursor, dinv, N, E, NB);
    k_fill_gemm<<<CB + RB, 256, 0, stream>>>(src, dst, dinv, cursor, edges, E, CB,
                                             xbf, wtbf, h_pre, N);
    k_gather1  <<<(N + 3) / 4, 256, 0, stream>>>(h_pre, row_ptr, edges, dinv, b1, h_mid, N, E);
    k_gather2  <<<(N + 3) / 4, 256, 0, stream>>>(h_mid, row_ptr, edges, dinv, Wmu, Wls,
                                                 bmu, bls, out, N, E);
}

// Round 7
// 227.420 us; speedup vs baseline: 2.3223x; 1.0384x over previous
//
#include <hip/hip_runtime.h>
#include <hip/hip_fp16.h>
#include <math.h>

// ---------------------------------------------------------------------------
// VariationalGCNEncoder: N=50000, E=800000, 128 -> 64 -> {32,32}
// R7: - gemm reads x f32 directly (in-register bf16 convert) -> xbf pass gone
//     - [count | gemm] fused (both LDS-free; R6 evidence: gemm ~free)
//     - gathers: bf16x2 per lane, 2 edges/step per wave, 16 edges in flight
//     - fill standalone (random-scatter write amplification is structural)
// Pipeline:
//   memset(counts) -> [gemm | count] -> scan1 -> scan23 -> fill
//   gather1: h = relu(A_norm . h_pre + b1)         (bf16)
//   gather2: out = (A_norm . h) @ [Wmu|Wls] + bias (f32)
// ---------------------------------------------------------------------------

typedef unsigned int uint;
typedef unsigned short ushort;
typedef __attribute__((ext_vector_type(8))) short short8;   // 8 bf16 = 4 VGPR
typedef __attribute__((ext_vector_type(4))) float f32x4;    // MFMA acc

__device__ __forceinline__ ushort f2bf(float x) {          // f32 -> bf16 RNE
    uint u = __float_as_uint(x);
    u += 0x7fffu + ((u >> 16) & 1u);
    return (ushort)(u >> 16);
}
__device__ __forceinline__ float bf2f(ushort h) {
    return __uint_as_float((uint)h << 16);
}
__device__ __forceinline__ float unpack_norm(uint r) {     // fp16 in high 16
    return __half2float(__ushort_as_half((ushort)(r >> 16)));
}

// blocks [0,GB): MFMA gemm h_pre = bf16(x) @ bf16(W1); blocks [GB,..): count
__global__ __launch_bounds__(256, 4) void k_count_gemm(
        const float* __restrict__ x, const float* __restrict__ W1,
        ushort* __restrict__ h_pre, int N, int GB,
        const int* __restrict__ dst, int* __restrict__ counts, int E) {
    const int tid = threadIdx.x;
    if (blockIdx.x >= GB) {                        // ---- degree count ----
        int i = (blockIdx.x - GB) * 256 + tid;
        if (i < E) atomicAdd(&counts[dst[i]], 1);
        return;
    }
    // ---- MFMA gemm: wave = 16 rows x 64 cols, k=128 in 4 chunks ----
    const int w = tid >> 6, l = tid & 63;
    const int m = l & 15, q = l >> 4;              // q = quad (0..3)
    const int row0 = blockIdx.x * 64 + w * 16;
    const size_t arow = (size_t)min(row0 + m, N - 1);   // clamp; store guarded
    f32x4 acc0 = {0.f, 0.f, 0.f, 0.f}, acc1 = acc0, acc2 = acc0, acc3 = acc0;
    #pragma unroll
    for (int kc = 0; kc < 4; ++kc) {
        const int kofs = kc * 32 + q * 8;
        // A fragment: x[arow][kofs..kofs+7] f32 -> bf16
        const float4* xr = (const float4*)(x + arow * 128 + kofs);
        float4 xa = xr[0], xb = xr[1];
        short8 a;
        a[0] = (short)f2bf(xa.x); a[1] = (short)f2bf(xa.y);
        a[2] = (short)f2bf(xa.z); a[3] = (short)f2bf(xa.w);
        a[4] = (short)f2bf(xb.x); a[5] = (short)f2bf(xb.y);
        a[6] = (short)f2bf(xb.z); a[7] = (short)f2bf(xb.w);
        // B fragments: W1[kofs+i][j*16+m] (L1-hot, 32 KB)
        short8 b0, b1, b2, b3;
        #pragma unroll
        for (int i = 0; i < 8; ++i) {
            const float* wk = W1 + (size_t)(kofs + i) * 64 + m;
            b0[i] = (short)f2bf(wk[0]);
            b1[i] = (short)f2bf(wk[16]);
            b2[i] = (short)f2bf(wk[32]);
            b3[i] = (short)f2bf(wk[48]);
        }
        acc0 = __builtin_amdgcn_mfma_f32_16x16x32_bf16(a, b0, acc0, 0, 0, 0);
        acc1 = __builtin_amdgcn_mfma_f32_16x16x32_bf16(a, b1, acc1, 0, 0, 0);
        acc2 = __builtin_amdgcn_mfma_f32_16x16x32_bf16(a, b2, acc2, 0, 0, 0);
        acc3 = __builtin_amdgcn_mfma_f32_16x16x32_bf16(a, b3, acc3, 0, 0, 0);
    }
    #pragma unroll
    for (int r = 0; r < 4; ++r) {                  // D: row=q*4+r, col=g*16+m
        int row = row0 + q * 4 + r;
        if (row >= N) continue;
        ushort* hr = h_pre + (size_t)row * 64 + m;
        hr[0]  = f2bf(acc0[r]);
        hr[16] = f2bf(acc1[r]);
        hr[32] = f2bf(acc2[r]);
        hr[48] = f2bf(acc3[r]);
    }
}

// per-block exclusive scan of counts -> row_ptr, block sums -> bsum
__global__ __launch_bounds__(256) void k_scan1(const int* __restrict__ counts,
                                               int* __restrict__ row_ptr,
                                               int* __restrict__ bsum, int N) {
    __shared__ int s[256];
    int t = threadIdx.x, i = blockIdx.x * 256 + t;
    int v = (i < N) ? counts[i] : 0;
    s[t] = v;
    __syncthreads();
    #pragma unroll
    for (int off = 1; off < 256; off <<= 1) {
        int x = (t >= off) ? s[t - off] : 0;
        __syncthreads();
        s[t] += x;
        __syncthreads();
    }
    if (i < N) row_ptr[i] = s[t] - v;
    if (t == 255) bsum[blockIdx.x] = s[255];
}

// fused scan2+scan3 (NB<=256)
__global__ __launch_bounds__(256) void k_scan23(
        int* __restrict__ row_ptr, const int* __restrict__ bsum,
        const int* __restrict__ counts, int* __restrict__ cursor,
        float* __restrict__ dinv, int N, int E, int NB) {
    __shared__ int s[256];
    const int t = threadIdx.x;
    s[t] = (t < blockIdx.x && t < NB) ? bsum[t] : 0;
    __syncthreads();
    #pragma unroll
    for (int off = 128; off >= 1; off >>= 1) {
        if (t < off) s[t] += s[t + off];
        __syncthreads();
    }
    const int offset = s[0];
    const int i = blockIdx.x * 256 + t;
    if (i < N) {
        int r = row_ptr[i] + offset;
        row_ptr[i] = r;
        cursor[i] = r;
        dinv[i] = rsqrtf((float)(counts[i] + 1));
    }
    if (blockIdx.x == 0 && t == 0) row_ptr[N] = E;
}

// packed edge record: low 16 = src (N < 65536), high 16 = fp16(norm)
__global__ __launch_bounds__(256) void k_fill(
        const int* __restrict__ src, const int* __restrict__ dst,
        const float* __restrict__ dinv, int* __restrict__ cursor,
        uint* __restrict__ edges, int E) {
    int e = blockIdx.x * blockDim.x + threadIdx.x;
    if (e >= E) return;
    int s = src[e], d = dst[e];
    int pos = atomicAdd(&cursor[d], 1);
    ushort nb = __half_as_ushort(__float2half(dinv[s] * dinv[d]));
    edges[pos] = (uint)s | ((uint)nb << 16);
}

// Shared gather core: 2 edges/step per wave (half-waves), bf16x2 lanes,
// 8-step unroll = 16 edges in flight. hp2 = rows as uint (bf16x2), hl in [0,32).
#define GATHER_CORE(HP2)                                                       \
    for (int base = beg; base < end; base += 64) {                             \
        int cnt = end - base; if (cnt > 64) cnt = 64;                          \
        uint mrec = edges[min(base + lane, E - 1)];                            \
        int steps = (cnt + 1) >> 1;                                            \
        for (int t = 0; t < steps; t += 8) {                                   \
            int e0 = 2*(t+0)+half, e1 = 2*(t+1)+half, e2 = 2*(t+2)+half,       \
                e3 = 2*(t+3)+half, e4 = 2*(t+4)+half, e5 = 2*(t+5)+half,       \
                e6 = 2*(t+6)+half, e7 = 2*(t+7)+half;                          \
            uint r0 = __shfl(mrec, min(e0, cnt-1));                            \
            uint r1 = __shfl(mrec, min(e1, cnt-1));                            \
            uint r2 = __shfl(mrec, min(e2, cnt-1));                            \
            uint r3 = __shfl(mrec, min(e3, cnt-1));                            \
            uint r4 = __shfl(mrec, min(e4, cnt-1));                            \
            uint r5 = __shfl(mrec, min(e5, cnt-1));                            \
            uint r6 = __shfl(mrec, min(e6, cnt-1));                            \
            uint r7 = __shfl(mrec, min(e7, cnt-1));                            \
            uint v0 = HP2[(size_t)(r0 & 0xffffu) * 32 + hl];                   \
            uint v1 = HP2[(size_t)(r1 & 0xffffu) * 32 + hl];                   \
            uint v2 = HP2[(size_t)(r2 & 0xffffu) * 32 + hl];                   \
            uint v3 = HP2[(size_t)(r3 & 0xffffu) * 32 + hl];                   \
            uint v4 = HP2[(size_t)(r4 & 0xffffu) * 32 + hl];                   \
            uint v5 = HP2[(size_t)(r5 & 0xffffu) * 32 + hl];                   \
            uint v6 = HP2[(size_t)(r6 & 0xffffu) * 32 + hl];                   \
            uint v7 = HP2[(size_t)(r7 & 0xffffu) * 32 + hl];                   \
            float w0 = (e0 < cnt) ? unpack_norm(r0) : 0.f;                     \
            float w1 = (e1 < cnt) ? unpack_norm(r1) : 0.f;                     \
            float w2 = (e2 < cnt) ? unpack_norm(r2) : 0.f;                     \
            float w3 = (e3 < cnt) ? unpack_norm(r3) : 0.f;                     \
            float w4 = (e4 < cnt) ? unpack_norm(r4) : 0.f;                     \
            float w5 = (e5 < cnt) ? unpack_norm(r5) : 0.f;                     \
            float w6 = (e6 < cnt) ? unpack_norm(r6) : 0.f;                     \
            float w7 = (e7 < cnt) ? unpack_norm(r7) : 0.f;                     \
            a0 = fmaf(w0, bf2f((ushort)v0), a0);                               \
            a1 = fmaf(w0, bf2f((ushort)(v0 >> 16)), a1);                       \
            a0 = fmaf(w1, bf2f((ushort)v1), a0);                               \
            a1 = fmaf(w1, bf2f((ushort)(v1 >> 16)), a1);                       \
            a0 = fmaf(w2, bf2f((ushort)v2), a0);                               \
            a1 = fmaf(w2, bf2f((ushort)(v2 >> 16)), a1);                       \
            a0 = fmaf(w3, bf2f((ushort)v3), a0);                               \
            a1 = fmaf(w3, bf2f((ushort)(v3 >> 16)), a1);                       \
            a0 = fmaf(w4, bf2f((ushort)v4), a0);                               \
            a1 = fmaf(w4, bf2f((ushort)(v4 >> 16)), a1);                       \
            a0 = fmaf(w5, bf2f((ushort)v5), a0);                               \
            a1 = fmaf(w5, bf2f((ushort)(v5 >> 16)), a1);                       \
            a0 = fmaf(w6, bf2f((ushort)v6), a0);                               \
            a1 = fmaf(w6, bf2f((ushort)(v6 >> 16)), a1);                       \
            a0 = fmaf(w7, bf2f((ushort)v7), a0);                               \
            a1 = fmaf(w7, bf2f((ushort)(v7 >> 16)), a1);                       \
        }                                                                      \
    }                                                                          \
    a0 += __shfl_xor(a0, 32);                                                  \
    a1 += __shfl_xor(a1, 32);

// h[n,2hl..2hl+1] = relu( dinv^2*h_pre + b1 + sum norm*h_pre[src] )  (bf16x2)
__global__ __launch_bounds__(256, 8) void k_gather1(
        const uint* __restrict__ hp2, const int* __restrict__ row_ptr,
        const uint* __restrict__ edges, const float* __restrict__ dinv,
        const float* __restrict__ b1, uint* __restrict__ ho2, int N, int E) {
    const int lane = threadIdx.x & 63;
    const int hl = lane & 31, half = lane >> 5;
    const int n = blockIdx.x * 4 + (threadIdx.x >> 6);
    if (n >= N) return;
    const int beg = row_ptr[n], end = row_ptr[n + 1];
    float a0 = 0.f, a1 = 0.f;
    if (half == 0) {
        uint sv = hp2[(size_t)n * 32 + hl];
        float dv = dinv[n];
        float2 b = ((const float2*)b1)[hl];
        a0 = dv * dv * bf2f((ushort)sv) + b.x;
        a1 = dv * dv * bf2f((ushort)(sv >> 16)) + b.y;
    }
    GATHER_CORE(hp2)
    if (half == 0) {
        uint p = (uint)f2bf(fmaxf(a0, 0.f)) | ((uint)f2bf(fmaxf(a1, 0.f)) << 16);
        ho2[(size_t)n * 32 + hl] = p;
    }
}

// g = A_norm . h;  out[n,col] = sum_k g[k]*W[k][col] + bias (mu | logstd)
__global__ __launch_bounds__(256, 8) void k_gather2(
        const uint* __restrict__ hp2, const int* __restrict__ row_ptr,
        const uint* __restrict__ edges, const float* __restrict__ dinv,
        const float* __restrict__ Wmu, const float* __restrict__ Wls,
        const float* __restrict__ bmu, const float* __restrict__ bls,
        float* __restrict__ out, int N, int E) {
    __shared__ float hs[4][64];    // per-wave gathered row (1 KB)
    const int lane = threadIdx.x & 63;
    const int hl = lane & 31, half = lane >> 5;
    const int w = threadIdx.x >> 6;
    const int n = blockIdx.x * 4 + w;
    if (n >= N) return;
    const int beg = row_ptr[n], end = row_ptr[n + 1];
    float a0 = 0.f, a1 = 0.f;
    if (half == 0) {
        uint sv = hp2[(size_t)n * 32 + hl];
        float dv = dinv[n];
        a0 = dv * dv * bf2f((ushort)sv);
        a1 = dv * dv * bf2f((ushort)(sv >> 16));
    }
    GATHER_CORE(hp2)
    if (half == 0) {
        float2 p; p.x = a0; p.y = a1;
        *(float2*)&hs[w][2 * hl] = p;          // g[2hl], g[2hl+1]
    }
    // epilogue: out_row = g @ [Wmu|Wls] + bias ; W from global (L1-hot)
    const float* Wsel = (lane < 32) ? (Wmu + lane) : (Wls + (lane - 32));
    const float bias  = (lane < 32) ? bmu[lane] : bls[lane - 32];
    float c0 = 0.f, c1 = 0.f, c2 = 0.f, c3 = 0.f;
    #pragma unroll 4
    for (int k = 0; k < 64; k += 4) {
        c0 = fmaf(hs[w][k + 0], Wsel[(k + 0) * 32], c0);
        c1 = fmaf(hs[w][k + 1], Wsel[(k + 1) * 32], c1);
        c2 = fmaf(hs[w][k + 2], Wsel[(k + 2) * 32], c2);
        c3 = fmaf(hs[w][k + 3], Wsel[(k + 3) * 32], c3);
    }
    float t = (c0 + c1) + (c2 + c3) + bias;
    if (lane < 32) out[(size_t)n * 32 + lane] = t;
    else           out[(size_t)N * 32 + (size_t)n * 32 + (lane - 32)] = t;
}

extern "C" void kernel_launch(void* const* d_in, const int* in_sizes, int n_in,
                              void* d_out, int out_size, void* d_ws, size_t ws_size,
                              hipStream_t stream) {
    const float* x   = (const float*)d_in[0];
    const int*   ei  = (const int*)d_in[1];
    const float* W1  = (const float*)d_in[2];
    const float* b1  = (const float*)d_in[3];
    const float* Wmu = (const float*)d_in[4];
    const float* bmu = (const float*)d_in[5];
    const float* Wls = (const float*)d_in[6];
    const float* bls = (const float*)d_in[7];
    float* out = (float*)d_out;

    const int N = in_sizes[0] / 128;          // 50000  (< 65536: u16 src pack)
    const int E = in_sizes[1] / 2;            // 800000
    const int* src = ei;
    const int* dst = ei + E;
    const int NB = (N + 255) / 256;           // scan blocks (196 <= 256)
    const int CB = (E + 255) / 256;           // count / fill blocks
    const int GB = (N + 63) / 64;             // gemm row-tile blocks

    char* w = (char*)d_ws;
    auto carve = [&](size_t bytes) { char* p = w; w += (bytes + 1023) & ~(size_t)1023; return p; };
    int*    counts  = (int*)   carve((size_t)N * 4);
    int*    row_ptr = (int*)   carve((size_t)(N + 1) * 4);
    int*    cursor  = (int*)   carve((size_t)N * 4);
    int*    bsum    = (int*)   carve(256 * 4);
    float*  dinv    = (float*) carve((size_t)N * 4);
    uint*   edges   = (uint*)  carve((size_t)E * 4);
    ushort* h_pre   = (ushort*)carve((size_t)N * 64 * 2);   // bf16
    ushort* h_mid   = (ushort*)carve((size_t)N * 64 * 2);   // bf16

    hipMemsetAsync(counts, 0, (size_t)N * 4, stream);
    k_count_gemm<<<GB + CB, 256, 0, stream>>>(x, W1, h_pre, N, GB, dst, counts, E);
    k_scan1     <<<NB, 256, 0, stream>>>(counts, row_ptr, bsum, N);
    k_scan23    <<<NB, 256, 0, stream>>>(row_ptr, bsum, counts, cursor, dinv, N, E, NB);
    k_fill      <<<CB, 256, 0, stream>>>(src, dst, dinv, cursor, edges, E);
    k_gather1   <<<(N + 3) / 4, 256, 0, stream>>>((const uint*)h_pre, row_ptr, edges,
                                                  dinv, b1, (uint*)h_mid, N, E);
    k_gather2   <<<(N + 3) / 4, 256, 0, stream>>>((const uint*)h_mid, row_ptr, edges,
                                                  dinv, Wmu, Wls, bmu, bls, out, N, E);
}